// Round 3
// baseline (593.578 us; speedup 1.0000x reference)
//
#include <hip/hip_runtime.h>
#include <stdint.h>

// Problem constants (B=2, L=2048 -> T=4096)
#define T_TOK 4096
#define D_DIM 1024
#define H_DIM 512
#define E_NUM 16
#define S_DIM 2048

typedef __attribute__((ext_vector_type(8))) __bf16 bf16x8;
typedef __attribute__((ext_vector_type(4))) float f32x4;

__device__ __forceinline__ uint16_t f2bf(float f) {
  uint32_t u = __float_as_uint(f);
  u += 0x7fffu + ((u >> 16) & 1u);   // round-to-nearest-even
  return (uint16_t)(u >> 16);
}

__device__ __forceinline__ void gl_lds16(const void* g, void* l) {
  __builtin_amdgcn_global_load_lds(
      (const __attribute__((address_space(1))) void*)g,
      (__attribute__((address_space(3))) void*)l, 16, 0, 0);
}

__device__ __forceinline__ float silu_f(float v) {
  return v / (1.f + __expf(-v));
}

// ---------------- fp32 -> bf16 cast ----------------
__global__ void k_cast(const float* __restrict__ in, uint16_t* __restrict__ out, int n4) {
  int i = blockIdx.x * 256 + threadIdx.x;
  if (i >= n4) return;
  float4 v = ((const float4*)in)[i];
  ushort4 o;
  o.x = f2bf(v.x); o.y = f2bf(v.y); o.z = f2bf(v.z); o.w = f2bf(v.w);
  ((ushort4*)out)[i] = o;
}

// ---------------- gw transpose: [E][D] -> [D/4][E] of float4 ----------------
// gwT4[k4*E_NUM + e] = float4(gw[e*D + 4*k4 .. 4*k4+3])
__global__ void k_gwT(const float* __restrict__ gw, float4* __restrict__ gwT4) {
  int tid = blockIdx.x * 256 + threadIdx.x;  // 4096 threads
  if (tid >= E_NUM * (D_DIM / 4)) return;
  int k4 = tid & (D_DIM / 4 - 1);
  int e = tid >> 8;
  float4 v = ((const float4*)(gw + (size_t)e * D_DIM))[k4];
  gwT4[(size_t)k4 * E_NUM + e] = v;
}

// ---------------- router: fp32 logits, in-register top-2 ----------------
__global__ void k_zero_counts(int* counts) {
  if (threadIdx.x < E_NUM) counts[threadIdx.x] = 0;
}

__global__ __launch_bounds__(256) void k_router(
    const float* __restrict__ x, const float4* __restrict__ gwT4,
    int* __restrict__ top_idx, float* __restrict__ top_w,
    int* __restrict__ counts) {
  const int wid = threadIdx.x >> 6, lane = threadIdx.x & 63;
  const int t = blockIdx.x * 4 + wid;
  const int e = lane & 15, q = lane >> 4;
  // lane accumulates dot(x[t, q*256:(q+1)*256], gw[e, same range])
  const float4* xr4 = (const float4*)(x + (size_t)t * D_DIM) + q * 64;
  const float4* g4 = gwT4 + (size_t)q * 64 * E_NUM + e;
  float acc = 0.f;
#pragma unroll 8
  for (int i = 0; i < 64; i++) {
    float4 xv = xr4[i];
    float4 gv = g4[(size_t)i * E_NUM];
    acc += xv.x * gv.x + xv.y * gv.y + xv.z * gv.z + xv.w * gv.w;
  }
  // reduce over q (4 replicas per expert)
  acc += __shfl_xor(acc, 16, 64);
  acc += __shfl_xor(acc, 32, 64);
  // every lane now holds the logit of expert e. top-2 via 16-lane butterfly.
  float v1 = acc; int i1 = e;
#pragma unroll
  for (int off = 1; off < 16; off <<= 1) {
    float ov = __shfl_xor(v1, off, 64);
    int oi = __shfl_xor(i1, off, 64);
    if (ov > v1 || (ov == v1 && oi < i1)) { v1 = ov; i1 = oi; }
  }
  float v2s = (e == i1) ? -1e30f : acc;
  float v2 = v2s; int i2 = e;
#pragma unroll
  for (int off = 1; off < 16; off <<= 1) {
    float ov = __shfl_xor(v2, off, 64);
    int oi = __shfl_xor(i2, off, 64);
    if (ov > v2 || (ov == v2 && oi < i2)) { v2 = ov; i2 = oi; }
  }
  if (lane == 0) {
    float w0 = 1.f / (1.f + __expf(v2 - v1));
    top_idx[t * 2] = i1; top_idx[t * 2 + 1] = i2;
    top_w[t * 2] = w0;  top_w[t * 2 + 1] = 1.f - w0;
    atomicAdd(&counts[i1], 1);
    atomicAdd(&counts[i2], 1);
  }
}

__global__ void k_offsets(const int* __restrict__ counts, int* __restrict__ offsets,
                          int* __restrict__ cursor) {
  if (threadIdx.x == 0) {
    int s = 0;
    for (int e = 0; e < E_NUM; e++) { offsets[e] = s; cursor[e] = s; s += counts[e]; }
    offsets[E_NUM] = s;
  }
}

__global__ void k_fill(const int* __restrict__ top_idx, const float* __restrict__ top_w,
                       int* __restrict__ cursor, int* __restrict__ slot_token,
                       float* __restrict__ slot_w, int* __restrict__ slot_of) {
  int id = blockIdx.x * 256 + threadIdx.x;  // 2*T entries
  if (id >= 2 * T_TOK) return;
  int t = id >> 1;
  int e = top_idx[id];
  int slot = atomicAdd(&cursor[e], 1);
  slot_token[slot] = t;
  slot_w[slot] = top_w[id];
  slot_of[id] = slot;
}

// ---------------- GEMM core helpers ----------------
// LDS tiles: [128 rows][32 cols] bf16, row-major (K contiguous). No padding
// (global_load_lds requires contiguous lane order). Frags: A row = lane&15,
// k = (lane>>4)*8 + j (ds_read_b128). C/D: col = lane&15, row = (lane>>4)*4+r.

// ---------------- G1: dual GEMM, epilogue silu(a1)*a2 -> Hs bf16 ----------------
__global__ __launch_bounds__(256) void k_dual_gemm_silu(
    const uint16_t* __restrict__ xb, const uint16_t* __restrict__ b1,
    const uint16_t* __restrict__ b2, uint16_t* __restrict__ hs) {
  __shared__ uint16_t sA[128 * 32], sB1[128 * 32], sB2[128 * 32];
  const int tid = threadIdx.x, lane = tid & 63, wid = tid >> 6;
  const int wm = wid >> 1, wn = wid & 1;
  const int bm0 = blockIdx.x * 128, bn0 = blockIdx.y * 128;

  f32x4 acc1[4][4], acc2[4][4];
#pragma unroll
  for (int i = 0; i < 4; i++)
#pragma unroll
    for (int j = 0; j < 4; j++) {
      acc1[i][j] = (f32x4){0.f, 0.f, 0.f, 0.f};
      acc2[i][j] = (f32x4){0.f, 0.f, 0.f, 0.f};
    }

  const int row0 = tid >> 2, col8 = (tid & 3) * 8;
  const uint16_t* ga0 = xb + (size_t)(bm0 + row0) * D_DIM + col8;
  const uint16_t* ga1 = ga0 + 64 * D_DIM;
  const uint16_t* gb10 = b1 + (size_t)(bn0 + row0) * D_DIM + col8;
  const uint16_t* gb11 = gb10 + 64 * D_DIM;
  const uint16_t* gb20 = b2 + (size_t)(bn0 + row0) * D_DIM + col8;
  const uint16_t* gb21 = gb20 + 64 * D_DIM;
  uint16_t* lA0 = sA + wid * 512;  uint16_t* lA1 = sA + 2048 + wid * 512;
  uint16_t* lB10 = sB1 + wid * 512; uint16_t* lB11 = sB1 + 2048 + wid * 512;
  uint16_t* lB20 = sB2 + wid * 512; uint16_t* lB21 = sB2 + 2048 + wid * 512;

  const int r = lane & 15, q = lane >> 4;
  for (int kt = 0; kt < D_DIM; kt += 32) {
    gl_lds16(ga0, lA0);  gl_lds16(ga1, lA1);
    gl_lds16(gb10, lB10); gl_lds16(gb11, lB11);
    gl_lds16(gb20, lB20); gl_lds16(gb21, lB21);
    ga0 += 32; ga1 += 32; gb10 += 32; gb11 += 32; gb20 += 32; gb21 += 32;
    __syncthreads();
    bf16x8 a[4];
#pragma unroll
    for (int i = 0; i < 4; i++)
      a[i] = *(const bf16x8*)(sA + (wm * 64 + i * 16 + r) * 32 + q * 8);
#pragma unroll
    for (int j = 0; j < 4; j++) {
      bf16x8 b = *(const bf16x8*)(sB1 + (wn * 64 + j * 16 + r) * 32 + q * 8);
#pragma unroll
      for (int i = 0; i < 4; i++)
        acc1[i][j] = __builtin_amdgcn_mfma_f32_16x16x32_bf16(a[i], b, acc1[i][j], 0, 0, 0);
    }
#pragma unroll
    for (int j = 0; j < 4; j++) {
      bf16x8 b = *(const bf16x8*)(sB2 + (wn * 64 + j * 16 + r) * 32 + q * 8);
#pragma unroll
      for (int i = 0; i < 4; i++)
        acc2[i][j] = __builtin_amdgcn_mfma_f32_16x16x32_bf16(a[i], b, acc2[i][j], 0, 0, 0);
    }
    __syncthreads();
  }
#pragma unroll
  for (int i = 0; i < 4; i++)
#pragma unroll
    for (int j = 0; j < 4; j++)
#pragma unroll
      for (int rr = 0; rr < 4; rr++) {
        int row = bm0 + wm * 64 + i * 16 + q * 4 + rr;
        int col = bn0 + wn * 64 + j * 16 + r;
        float aa = acc1[i][j][rr], bb = acc2[i][j][rr];
        hs[(size_t)row * S_DIM + col] = f2bf(silu_f(aa) * bb);
      }
}

// ---------------- G2: shared = Hs @ sfc3^T -> fp32 stores to out ----------------
__global__ __launch_bounds__(256) void k_gemm_shared_out(
    const uint16_t* __restrict__ hsb, const uint16_t* __restrict__ b,
    float* __restrict__ out) {
  __shared__ uint16_t sA[128 * 32], sB[128 * 32];
  const int tid = threadIdx.x, lane = tid & 63, wid = tid >> 6;
  const int wm = wid >> 1, wn = wid & 1;
  const int bm0 = blockIdx.x * 128, bn0 = blockIdx.y * 128;
  f32x4 acc[4][4];
#pragma unroll
  for (int i = 0; i < 4; i++)
#pragma unroll
    for (int j = 0; j < 4; j++) acc[i][j] = (f32x4){0.f, 0.f, 0.f, 0.f};

  const int row0 = tid >> 2, col8 = (tid & 3) * 8;
  const uint16_t* ga0 = hsb + (size_t)(bm0 + row0) * S_DIM + col8;
  const uint16_t* ga1 = ga0 + (size_t)64 * S_DIM;
  const uint16_t* gb0 = b + (size_t)(bn0 + row0) * S_DIM + col8;
  const uint16_t* gb1 = gb0 + (size_t)64 * S_DIM;
  uint16_t* lA0 = sA + wid * 512; uint16_t* lA1 = sA + 2048 + wid * 512;
  uint16_t* lB0 = sB + wid * 512; uint16_t* lB1 = sB + 2048 + wid * 512;
  const int r = lane & 15, q = lane >> 4;
  for (int kt = 0; kt < S_DIM; kt += 32) {
    gl_lds16(ga0, lA0); gl_lds16(ga1, lA1);
    gl_lds16(gb0, lB0); gl_lds16(gb1, lB1);
    ga0 += 32; ga1 += 32; gb0 += 32; gb1 += 32;
    __syncthreads();
    bf16x8 a[4], bb[4];
#pragma unroll
    for (int i = 0; i < 4; i++)
      a[i] = *(const bf16x8*)(sA + (wm * 64 + i * 16 + r) * 32 + q * 8);
#pragma unroll
    for (int j = 0; j < 4; j++)
      bb[j] = *(const bf16x8*)(sB + (wn * 64 + j * 16 + r) * 32 + q * 8);
#pragma unroll
    for (int i = 0; i < 4; i++)
#pragma unroll
      for (int j = 0; j < 4; j++)
        acc[i][j] = __builtin_amdgcn_mfma_f32_16x16x32_bf16(a[i], bb[j], acc[i][j], 0, 0, 0);
    __syncthreads();
  }
#pragma unroll
  for (int i = 0; i < 4; i++)
#pragma unroll
    for (int j = 0; j < 4; j++)
#pragma unroll
      for (int rr = 0; rr < 4; rr++) {
        int row = bm0 + wm * 64 + i * 16 + q * 4 + rr;
        int col = bn0 + wn * 64 + j * 16 + r;
        out[(size_t)row * D_DIM + col] = acc[i][j][rr];
      }
}

// ---------------- M1: grouped h = silu(Xg @ w1[e]^T) -> bf16 ----------------
__global__ __launch_bounds__(256) void k_moe1(
    const uint16_t* __restrict__ xb, const uint16_t* __restrict__ w1b,
    const int* __restrict__ offsets, const int* __restrict__ slot_token,
    uint16_t* __restrict__ hbuf) {
  const int e = blockIdx.z;
  const int base = offsets[e];
  const int ne = offsets[e + 1] - base;
  const int m0 = blockIdx.x * 128;
  if (m0 >= ne) return;
  const int n0 = blockIdx.y * 128;  // over H=512
  __shared__ uint16_t sA[128 * 32], sB[128 * 32];
  const int tid = threadIdx.x, lane = tid & 63, wid = tid >> 6;
  const int wm = wid >> 1, wn = wid & 1;
  f32x4 acc[4][4];
#pragma unroll
  for (int i = 0; i < 4; i++)
#pragma unroll
    for (int j = 0; j < 4; j++) acc[i][j] = (f32x4){0.f, 0.f, 0.f, 0.f};

  const int row0 = tid >> 2, col8 = (tid & 3) * 8;
  const int e0 = min(m0 + row0, ne - 1);
  const int e1 = min(m0 + row0 + 64, ne - 1);
  const uint16_t* ga0 = xb + (size_t)slot_token[base + e0] * D_DIM + col8;
  const uint16_t* ga1 = xb + (size_t)slot_token[base + e1] * D_DIM + col8;
  const uint16_t* wbase = w1b + (size_t)e * H_DIM * D_DIM;
  const uint16_t* gb0 = wbase + (size_t)(n0 + row0) * D_DIM + col8;
  const uint16_t* gb1 = gb0 + 64 * D_DIM;
  uint16_t* lA0 = sA + wid * 512; uint16_t* lA1 = sA + 2048 + wid * 512;
  uint16_t* lB0 = sB + wid * 512; uint16_t* lB1 = sB + 2048 + wid * 512;
  const int r = lane & 15, q = lane >> 4;
  for (int kt = 0; kt < D_DIM; kt += 32) {
    gl_lds16(ga0, lA0); gl_lds16(ga1, lA1);
    gl_lds16(gb0, lB0); gl_lds16(gb1, lB1);
    ga0 += 32; ga1 += 32; gb0 += 32; gb1 += 32;
    __syncthreads();
    bf16x8 a[4], bb[4];
#pragma unroll
    for (int i = 0; i < 4; i++)
      a[i] = *(const bf16x8*)(sA + (wm * 64 + i * 16 + r) * 32 + q * 8);
#pragma unroll
    for (int j = 0; j < 4; j++)
      bb[j] = *(const bf16x8*)(sB + (wn * 64 + j * 16 + r) * 32 + q * 8);
#pragma unroll
    for (int i = 0; i < 4; i++)
#pragma unroll
      for (int j = 0; j < 4; j++)
        acc[i][j] = __builtin_amdgcn_mfma_f32_16x16x32_bf16(a[i], bb[j], acc[i][j], 0, 0, 0);
    __syncthreads();
  }
#pragma unroll
  for (int i = 0; i < 4; i++)
#pragma unroll
    for (int j = 0; j < 4; j++)
#pragma unroll
      for (int rr = 0; rr < 4; rr++) {
        int ent = m0 + wm * 64 + i * 16 + q * 4 + rr;
        if (ent < ne) {
          int col = n0 + wn * 64 + j * 16 + r;
          hbuf[(size_t)(base + ent) * H_DIM + col] = f2bf(silu_f(acc[i][j][rr]));
        }
      }
}

// ---------------- M2: moe = h @ w2[e]^T, dense per-slot stores (NO atomics) ----------------
__global__ __launch_bounds__(256) void k_moe2(
    const uint16_t* __restrict__ hbuf, const uint16_t* __restrict__ w2b,
    const int* __restrict__ offsets, const int* __restrict__ slot_token,
    const float* __restrict__ slot_w, float* __restrict__ slot_out) {
  const int e = blockIdx.z;
  const int base = offsets[e];
  const int ne = offsets[e + 1] - base;
  const int m0 = blockIdx.x * 128;
  if (m0 >= ne) return;
  const int n0 = blockIdx.y * 128;  // over D=1024
  __shared__ uint16_t sA[128 * 32], sB[128 * 32];
  const int tid = threadIdx.x, lane = tid & 63, wid = tid >> 6;
  const int wm = wid >> 1, wn = wid & 1;
  f32x4 acc[4][4];
#pragma unroll
  for (int i = 0; i < 4; i++)
#pragma unroll
    for (int j = 0; j < 4; j++) acc[i][j] = (f32x4){0.f, 0.f, 0.f, 0.f};

  const int row0 = tid >> 2, col8 = (tid & 3) * 8;
  const int e0 = min(m0 + row0, ne - 1);
  const int e1 = min(m0 + row0 + 64, ne - 1);
  const uint16_t* ga0 = hbuf + (size_t)(base + e0) * H_DIM + col8;
  const uint16_t* ga1 = hbuf + (size_t)(base + e1) * H_DIM + col8;
  const uint16_t* wbase = w2b + (size_t)e * D_DIM * H_DIM;
  const uint16_t* gb0 = wbase + (size_t)(n0 + row0) * H_DIM + col8;
  const uint16_t* gb1 = gb0 + 64 * H_DIM;
  uint16_t* lA0 = sA + wid * 512; uint16_t* lA1 = sA + 2048 + wid * 512;
  uint16_t* lB0 = sB + wid * 512; uint16_t* lB1 = sB + 2048 + wid * 512;
  const int r = lane & 15, q = lane >> 4;
  for (int kt = 0; kt < H_DIM; kt += 32) {
    gl_lds16(ga0, lA0); gl_lds16(ga1, lA1);
    gl_lds16(gb0, lB0); gl_lds16(gb1, lB1);
    ga0 += 32; ga1 += 32; gb0 += 32; gb1 += 32;
    __syncthreads();
    bf16x8 a[4], bb[4];
#pragma unroll
    for (int i = 0; i < 4; i++)
      a[i] = *(const bf16x8*)(sA + (wm * 64 + i * 16 + r) * 32 + q * 8);
#pragma unroll
    for (int j = 0; j < 4; j++)
      bb[j] = *(const bf16x8*)(sB + (wn * 64 + j * 16 + r) * 32 + q * 8);
#pragma unroll
    for (int i = 0; i < 4; i++)
#pragma unroll
      for (int j = 0; j < 4; j++)
        acc[i][j] = __builtin_amdgcn_mfma_f32_16x16x32_bf16(a[i], bb[j], acc[i][j], 0, 0, 0);
    __syncthreads();
  }
#pragma unroll
  for (int i = 0; i < 4; i++) {
    int ent_base = m0 + wm * 64 + i * 16 + q * 4;
#pragma unroll
    for (int rr = 0; rr < 4; rr++) {
      int ent = ent_base + rr;
      if (ent < ne) {
        float w = slot_w[base + ent];
        float* orow = slot_out + (size_t)(base + ent) * D_DIM;
#pragma unroll
        for (int j = 0; j < 4; j++) {
          int col = n0 + wn * 64 + j * 16 + r;
          orow[col] = w * acc[i][j][rr];
        }
      }
    }
  }
}

// ---------------- combine: out[t] += slot_out[slot0[t]] + slot_out[slot1[t]] ----------------
__global__ __launch_bounds__(256) void k_combine(
    const float* __restrict__ slot_out, const int* __restrict__ slot_of,
    float* __restrict__ out) {
  // one block handles one token's 1024 floats as 256 float4
  int t = blockIdx.x;
  int c = threadIdx.x;
  int s0 = slot_of[t * 2], s1 = slot_of[t * 2 + 1];
  float4 a = ((const float4*)(slot_out + (size_t)s0 * D_DIM))[c];
  float4 b = ((const float4*)(slot_out + (size_t)s1 * D_DIM))[c];
  float4* po = (float4*)(out + (size_t)t * D_DIM) + c;
  float4 o = *po;
  o.x += a.x + b.x; o.y += a.y + b.y; o.z += a.z + b.z; o.w += a.w + b.w;
  *po = o;
}

// ---------------- launch ----------------
extern "C" void kernel_launch(void* const* d_in, const int* in_sizes, int n_in,
                              void* d_out, int out_size, void* d_ws, size_t ws_size,
                              hipStream_t stream) {
  const float* x     = (const float*)d_in[0];
  const float* gatew = (const float*)d_in[1];
  const float* w1    = (const float*)d_in[2];
  const float* w2    = (const float*)d_in[3];
  const float* sfc1  = (const float*)d_in[4];
  const float* sfc2  = (const float*)d_in[5];
  const float* sfc3  = (const float*)d_in[6];
  float* out = (float*)d_out;

  uint8_t* ws = (uint8_t*)d_ws;
  size_t off = 0;
  auto alloc = [&](size_t bytes) {
    void* p = ws + off;
    off = (off + bytes + 255) & ~(size_t)255;
    return p;
  };
  uint16_t* xb    = (uint16_t*)alloc((size_t)T_TOK * D_DIM * 2);
  uint16_t* sfc1b = (uint16_t*)alloc((size_t)S_DIM * D_DIM * 2);
  uint16_t* sfc2b = (uint16_t*)alloc((size_t)S_DIM * D_DIM * 2);
  uint16_t* sfc3b = (uint16_t*)alloc((size_t)D_DIM * S_DIM * 2);
  uint16_t* w1b   = (uint16_t*)alloc((size_t)E_NUM * H_DIM * D_DIM * 2);
  uint16_t* w2b   = (uint16_t*)alloc((size_t)E_NUM * D_DIM * H_DIM * 2);
  uint16_t* hsb   = (uint16_t*)alloc((size_t)T_TOK * S_DIM * 2);
  uint16_t* hbuf  = (uint16_t*)alloc((size_t)2 * T_TOK * H_DIM * 2);
  float* slot_out = (float*)alloc((size_t)2 * T_TOK * D_DIM * 4);
  float4* gwT4    = (float4*)alloc((size_t)D_DIM / 4 * E_NUM * 16);
  int*   top_idx  = (int*)alloc((size_t)T_TOK * 2 * 4);
  float* top_w    = (float*)alloc((size_t)T_TOK * 2 * 4);
  int*   counts   = (int*)alloc(E_NUM * 4);
  int*   offsets  = (int*)alloc((E_NUM + 1) * 4);
  int*   cursor   = (int*)alloc(E_NUM * 4);
  int*   slot_token = (int*)alloc((size_t)2 * T_TOK * 4);
  float* slot_w   = (float*)alloc((size_t)2 * T_TOK * 4);
  int*   slot_of  = (int*)alloc((size_t)2 * T_TOK * 4);

  // 1. casts + gw transpose
  {
    int n4;
    n4 = T_TOK * D_DIM / 4;  k_cast<<<(n4 + 255) / 256, 256, 0, stream>>>(x, xb, n4);
    n4 = S_DIM * D_DIM / 4;  k_cast<<<(n4 + 255) / 256, 256, 0, stream>>>(sfc1, sfc1b, n4);
    n4 = S_DIM * D_DIM / 4;  k_cast<<<(n4 + 255) / 256, 256, 0, stream>>>(sfc2, sfc2b, n4);
    n4 = D_DIM * S_DIM / 4;  k_cast<<<(n4 + 255) / 256, 256, 0, stream>>>(sfc3, sfc3b, n4);
    n4 = E_NUM * H_DIM * D_DIM / 4; k_cast<<<(n4 + 255) / 256, 256, 0, stream>>>(w1, w1b, n4);
    n4 = E_NUM * D_DIM * H_DIM / 4; k_cast<<<(n4 + 255) / 256, 256, 0, stream>>>(w2, w2b, n4);
    k_gwT<<<(E_NUM * D_DIM / 4 + 255) / 256, 256, 0, stream>>>(gatew, gwT4);
  }
  // 2. router
  k_zero_counts<<<1, 64, 0, stream>>>(counts);
  k_router<<<T_TOK / 4, 256, 0, stream>>>(x, gwT4, top_idx, top_w, counts);
  k_offsets<<<1, 64, 0, stream>>>(counts, offsets, cursor);
  k_fill<<<(2 * T_TOK + 255) / 256, 256, 0, stream>>>(top_idx, top_w, cursor, slot_token, slot_w, slot_of);
  // 3. shared expert
  k_dual_gemm_silu<<<dim3(T_TOK / 128, S_DIM / 128), 256, 0, stream>>>(xb, sfc1b, sfc2b, hsb);
  k_gemm_shared_out<<<dim3(T_TOK / 128, D_DIM / 128), 256, 0, stream>>>(hsb, sfc3b, out);
  // 4. MoE grouped
  k_moe1<<<dim3(T_TOK / 128, H_DIM / 128, E_NUM), 256, 0, stream>>>(xb, w1b, offsets, slot_token, hbuf);
  k_moe2<<<dim3(T_TOK / 128, D_DIM / 128, E_NUM), 256, 0, stream>>>(hbuf, w2b, offsets, slot_token, slot_w, slot_out);
  // 5. combine MoE slots into output
  k_combine<<<T_TOK, 256, 0, stream>>>(slot_out, slot_of, out);
}

// Round 4
// 485.072 us; speedup vs baseline: 1.2237x; 1.2237x over previous
//
#include <hip/hip_runtime.h>
#include <stdint.h>

// Problem constants (B=2, L=2048 -> T=4096)
#define T_TOK 4096
#define D_DIM 1024
#define H_DIM 512
#define E_NUM 16
#define S_DIM 2048

typedef __attribute__((ext_vector_type(8))) __bf16 bf16x8;
typedef __attribute__((ext_vector_type(4))) float f32x4;

__device__ __forceinline__ uint16_t f2bf(float f) {
  uint32_t u = __float_as_uint(f);
  u += 0x7fffu + ((u >> 16) & 1u);   // round-to-nearest-even
  return (uint16_t)(u >> 16);
}

__device__ __forceinline__ void gl_lds16(const void* g, void* l) {
  __builtin_amdgcn_global_load_lds(
      (const __attribute__((address_space(1))) void*)g,
      (__attribute__((address_space(3))) void*)l, 16, 0, 0);
}

__device__ __forceinline__ float silu_f(float v) {
  return v / (1.f + __expf(-v));
}

// ---------------- fp32 -> bf16 cast ----------------
__global__ void k_cast(const float* __restrict__ in, uint16_t* __restrict__ out, int n4) {
  int i = blockIdx.x * 256 + threadIdx.x;
  if (i >= n4) return;
  float4 v = ((const float4*)in)[i];
  ushort4 o;
  o.x = f2bf(v.x); o.y = f2bf(v.y); o.z = f2bf(v.z); o.w = f2bf(v.w);
  ((ushort4*)out)[i] = o;
}

// ---------------- gw transpose: [E][D] -> [D/4][E] of float4 ----------------
__global__ void k_gwT(const float* __restrict__ gw, float4* __restrict__ gwT4) {
  int tid = blockIdx.x * 256 + threadIdx.x;  // 4096 threads
  if (tid >= E_NUM * (D_DIM / 4)) return;
  int k4 = tid & (D_DIM / 4 - 1);
  int e = tid >> 8;
  float4 v = ((const float4*)(gw + (size_t)e * D_DIM))[k4];
  gwT4[(size_t)k4 * E_NUM + e] = v;
}

// ---------------- router: fp32 logits, in-register top-2, NO atomics ----------------
__global__ __launch_bounds__(256) void k_router(
    const float* __restrict__ x, const float4* __restrict__ gwT4,
    int* __restrict__ top_idx, float* __restrict__ top_w) {
  const int wid = threadIdx.x >> 6, lane = threadIdx.x & 63;
  const int t = blockIdx.x * 4 + wid;
  const int e = lane & 15, q = lane >> 4;
  const float4* xr4 = (const float4*)(x + (size_t)t * D_DIM) + q * 64;
  const float4* g4 = gwT4 + (size_t)q * 64 * E_NUM + e;
  float acc = 0.f;
#pragma unroll 8
  for (int i = 0; i < 64; i++) {
    float4 xv = xr4[i];
    float4 gv = g4[(size_t)i * E_NUM];
    acc += xv.x * gv.x + xv.y * gv.y + xv.z * gv.z + xv.w * gv.w;
  }
  acc += __shfl_xor(acc, 16, 64);
  acc += __shfl_xor(acc, 32, 64);
  float v1 = acc; int i1 = e;
#pragma unroll
  for (int off = 1; off < 16; off <<= 1) {
    float ov = __shfl_xor(v1, off, 64);
    int oi = __shfl_xor(i1, off, 64);
    if (ov > v1 || (ov == v1 && oi < i1)) { v1 = ov; i1 = oi; }
  }
  float v2 = (e == i1) ? -1e30f : acc; int i2 = e;
#pragma unroll
  for (int off = 1; off < 16; off <<= 1) {
    float ov = __shfl_xor(v2, off, 64);
    int oi = __shfl_xor(i2, off, 64);
    if (ov > v2 || (ov == v2 && oi < i2)) { v2 = ov; i2 = oi; }
  }
  if (lane == 0) {
    float w0 = 1.f / (1.f + __expf(v2 - v1));
    top_idx[t * 2] = i1; top_idx[t * 2 + 1] = i2;
    top_w[t * 2] = w0;  top_w[t * 2 + 1] = 1.f - w0;
  }
}

// ---------------- counting sort (no global atomics) ----------------
// 2T = 8192 entries, 32 blocks x 256 threads.
__global__ __launch_bounds__(256) void k_hist(const int* __restrict__ top_idx,
                                              int* __restrict__ partial) {
  __shared__ int h[E_NUM];
  int tid = threadIdx.x;
  if (tid < E_NUM) h[tid] = 0;
  __syncthreads();
  int id = blockIdx.x * 256 + tid;
  atomicAdd(&h[top_idx[id]], 1);
  __syncthreads();
  if (tid < E_NUM) partial[blockIdx.x * E_NUM + tid] = h[tid];
}

__global__ void k_scan(const int* __restrict__ partial, int* __restrict__ bases,
                       int* __restrict__ offsets) {
  __shared__ int tot[E_NUM];
  int e = threadIdx.x;
  if (e < E_NUM) {
    int run = 0;
    for (int b = 0; b < 32; b++) { bases[b * E_NUM + e] = run; run += partial[b * E_NUM + e]; }
    tot[e] = run;
  }
  __syncthreads();
  if (e == 0) {
    int s = 0;
    for (int i = 0; i < E_NUM; i++) { offsets[i] = s; s += tot[i]; }
    offsets[E_NUM] = s;
  }
  __syncthreads();
  if (e < E_NUM) {
    int off = offsets[e];
    for (int b = 0; b < 32; b++) bases[b * E_NUM + e] += off;
  }
}

__global__ __launch_bounds__(256) void k_scatter(
    const int* __restrict__ top_idx, const float* __restrict__ top_w,
    const int* __restrict__ bases, int* __restrict__ slot_token,
    float* __restrict__ slot_w, int* __restrict__ slot_of) {
  __shared__ int cur[E_NUM];
  int tid = threadIdx.x;
  if (tid < E_NUM) cur[tid] = bases[blockIdx.x * E_NUM + tid];
  __syncthreads();
  int id = blockIdx.x * 256 + tid;
  int e = top_idx[id];
  int slot = atomicAdd(&cur[e], 1);   // LDS atomic — cheap
  slot_token[slot] = id >> 1;
  slot_w[slot] = top_w[id];
  slot_of[id] = slot;
}

// ---------------- GEMM core ----------------
// LDS tiles: [128 rows][32 cols] bf16, row-major (K contiguous). No padding
// (global_load_lds requires contiguous lane order). Frags: A row = lane&15,
// k = (lane>>4)*8 + j (ds_read_b128). C/D: col = lane&15, row = (lane>>4)*4+r.

// ---------------- G1: dual GEMM, epilogue silu(a1)*a2 -> Hs bf16 ----------------
__global__ __launch_bounds__(256) void k_dual_gemm_silu(
    const uint16_t* __restrict__ xb, const uint16_t* __restrict__ b1,
    const uint16_t* __restrict__ b2, uint16_t* __restrict__ hs) {
  __shared__ uint16_t sA[128 * 32], sB1[128 * 32], sB2[128 * 32];
  const int tid = threadIdx.x, lane = tid & 63, wid = tid >> 6;
  const int wm = wid >> 1, wn = wid & 1;
  const int bm0 = blockIdx.x * 128, bn0 = blockIdx.y * 128;

  f32x4 acc1[4][4], acc2[4][4];
#pragma unroll
  for (int i = 0; i < 4; i++)
#pragma unroll
    for (int j = 0; j < 4; j++) {
      acc1[i][j] = (f32x4){0.f, 0.f, 0.f, 0.f};
      acc2[i][j] = (f32x4){0.f, 0.f, 0.f, 0.f};
    }

  const int row0 = tid >> 2, col8 = (tid & 3) * 8;
  const uint16_t* ga0 = xb + (size_t)(bm0 + row0) * D_DIM + col8;
  const uint16_t* ga1 = ga0 + 64 * D_DIM;
  const uint16_t* gb10 = b1 + (size_t)(bn0 + row0) * D_DIM + col8;
  const uint16_t* gb11 = gb10 + 64 * D_DIM;
  const uint16_t* gb20 = b2 + (size_t)(bn0 + row0) * D_DIM + col8;
  const uint16_t* gb21 = gb20 + 64 * D_DIM;
  uint16_t* lA0 = sA + wid * 512;  uint16_t* lA1 = sA + 2048 + wid * 512;
  uint16_t* lB10 = sB1 + wid * 512; uint16_t* lB11 = sB1 + 2048 + wid * 512;
  uint16_t* lB20 = sB2 + wid * 512; uint16_t* lB21 = sB2 + 2048 + wid * 512;

  const int r = lane & 15, q = lane >> 4;
  for (int kt = 0; kt < D_DIM; kt += 32) {
    gl_lds16(ga0, lA0);  gl_lds16(ga1, lA1);
    gl_lds16(gb10, lB10); gl_lds16(gb11, lB11);
    gl_lds16(gb20, lB20); gl_lds16(gb21, lB21);
    ga0 += 32; ga1 += 32; gb10 += 32; gb11 += 32; gb20 += 32; gb21 += 32;
    __syncthreads();
    bf16x8 a[4];
#pragma unroll
    for (int i = 0; i < 4; i++)
      a[i] = *(const bf16x8*)(sA + (wm * 64 + i * 16 + r) * 32 + q * 8);
#pragma unroll
    for (int j = 0; j < 4; j++) {
      bf16x8 b = *(const bf16x8*)(sB1 + (wn * 64 + j * 16 + r) * 32 + q * 8);
#pragma unroll
      for (int i = 0; i < 4; i++)
        acc1[i][j] = __builtin_amdgcn_mfma_f32_16x16x32_bf16(a[i], b, acc1[i][j], 0, 0, 0);
    }
#pragma unroll
    for (int j = 0; j < 4; j++) {
      bf16x8 b = *(const bf16x8*)(sB2 + (wn * 64 + j * 16 + r) * 32 + q * 8);
#pragma unroll
      for (int i = 0; i < 4; i++)
        acc2[i][j] = __builtin_amdgcn_mfma_f32_16x16x32_bf16(a[i], b, acc2[i][j], 0, 0, 0);
    }
    __syncthreads();
  }
#pragma unroll
  for (int i = 0; i < 4; i++)
#pragma unroll
    for (int j = 0; j < 4; j++)
#pragma unroll
      for (int rr = 0; rr < 4; rr++) {
        int row = bm0 + wm * 64 + i * 16 + q * 4 + rr;
        int col = bn0 + wn * 64 + j * 16 + r;
        float aa = acc1[i][j][rr], bb = acc2[i][j][rr];
        hs[(size_t)row * S_DIM + col] = f2bf(silu_f(aa) * bb);
      }
}

// ---------------- G2: shared = Hs @ sfc3^T -> fp32 stores to out ----------------
__global__ __launch_bounds__(256) void k_gemm_shared_out(
    const uint16_t* __restrict__ hsb, const uint16_t* __restrict__ b,
    float* __restrict__ out) {
  __shared__ uint16_t sA[128 * 32], sB[128 * 32];
  const int tid = threadIdx.x, lane = tid & 63, wid = tid >> 6;
  const int wm = wid >> 1, wn = wid & 1;
  const int bm0 = blockIdx.x * 128, bn0 = blockIdx.y * 128;
  f32x4 acc[4][4];
#pragma unroll
  for (int i = 0; i < 4; i++)
#pragma unroll
    for (int j = 0; j < 4; j++) acc[i][j] = (f32x4){0.f, 0.f, 0.f, 0.f};

  const int row0 = tid >> 2, col8 = (tid & 3) * 8;
  const uint16_t* ga0 = hsb + (size_t)(bm0 + row0) * S_DIM + col8;
  const uint16_t* ga1 = ga0 + (size_t)64 * S_DIM;
  const uint16_t* gb0 = b + (size_t)(bn0 + row0) * S_DIM + col8;
  const uint16_t* gb1 = gb0 + (size_t)64 * S_DIM;
  uint16_t* lA0 = sA + wid * 512; uint16_t* lA1 = sA + 2048 + wid * 512;
  uint16_t* lB0 = sB + wid * 512; uint16_t* lB1 = sB + 2048 + wid * 512;
  const int r = lane & 15, q = lane >> 4;
  for (int kt = 0; kt < S_DIM; kt += 32) {
    gl_lds16(ga0, lA0); gl_lds16(ga1, lA1);
    gl_lds16(gb0, lB0); gl_lds16(gb1, lB1);
    ga0 += 32; ga1 += 32; gb0 += 32; gb1 += 32;
    __syncthreads();
    bf16x8 a[4], bb[4];
#pragma unroll
    for (int i = 0; i < 4; i++)
      a[i] = *(const bf16x8*)(sA + (wm * 64 + i * 16 + r) * 32 + q * 8);
#pragma unroll
    for (int j = 0; j < 4; j++)
      bb[j] = *(const bf16x8*)(sB + (wn * 64 + j * 16 + r) * 32 + q * 8);
#pragma unroll
    for (int i = 0; i < 4; i++)
#pragma unroll
      for (int j = 0; j < 4; j++)
        acc[i][j] = __builtin_amdgcn_mfma_f32_16x16x32_bf16(a[i], bb[j], acc[i][j], 0, 0, 0);
    __syncthreads();
  }
#pragma unroll
  for (int i = 0; i < 4; i++)
#pragma unroll
    for (int j = 0; j < 4; j++)
#pragma unroll
      for (int rr = 0; rr < 4; rr++) {
        int row = bm0 + wm * 64 + i * 16 + q * 4 + rr;
        int col = bn0 + wn * 64 + j * 16 + r;
        out[(size_t)row * D_DIM + col] = acc[i][j][rr];
      }
}

// ---------------- M1: grouped h = silu(Xg @ w1[e]^T) -> bf16 ----------------
__global__ __launch_bounds__(256) void k_moe1(
    const uint16_t* __restrict__ xb, const uint16_t* __restrict__ w1b,
    const int* __restrict__ offsets, const int* __restrict__ slot_token,
    uint16_t* __restrict__ hbuf) {
  const int e = blockIdx.z;
  const int base = offsets[e];
  const int ne = offsets[e + 1] - base;
  const int m0 = blockIdx.x * 128;
  if (m0 >= ne) return;
  const int n0 = blockIdx.y * 128;  // over H=512
  __shared__ uint16_t sA[128 * 32], sB[128 * 32];
  const int tid = threadIdx.x, lane = tid & 63, wid = tid >> 6;
  const int wm = wid >> 1, wn = wid & 1;
  f32x4 acc[4][4];
#pragma unroll
  for (int i = 0; i < 4; i++)
#pragma unroll
    for (int j = 0; j < 4; j++) acc[i][j] = (f32x4){0.f, 0.f, 0.f, 0.f};

  const int row0 = tid >> 2, col8 = (tid & 3) * 8;
  const int e0 = min(m0 + row0, ne - 1);
  const int e1 = min(m0 + row0 + 64, ne - 1);
  const uint16_t* ga0 = xb + (size_t)slot_token[base + e0] * D_DIM + col8;
  const uint16_t* ga1 = xb + (size_t)slot_token[base + e1] * D_DIM + col8;
  const uint16_t* wbase = w1b + (size_t)e * H_DIM * D_DIM;
  const uint16_t* gb0 = wbase + (size_t)(n0 + row0) * D_DIM + col8;
  const uint16_t* gb1 = gb0 + 64 * D_DIM;
  uint16_t* lA0 = sA + wid * 512; uint16_t* lA1 = sA + 2048 + wid * 512;
  uint16_t* lB0 = sB + wid * 512; uint16_t* lB1 = sB + 2048 + wid * 512;
  const int r = lane & 15, q = lane >> 4;
  for (int kt = 0; kt < D_DIM; kt += 32) {
    gl_lds16(ga0, lA0); gl_lds16(ga1, lA1);
    gl_lds16(gb0, lB0); gl_lds16(gb1, lB1);
    ga0 += 32; ga1 += 32; gb0 += 32; gb1 += 32;
    __syncthreads();
    bf16x8 a[4], bb[4];
#pragma unroll
    for (int i = 0; i < 4; i++)
      a[i] = *(const bf16x8*)(sA + (wm * 64 + i * 16 + r) * 32 + q * 8);
#pragma unroll
    for (int j = 0; j < 4; j++)
      bb[j] = *(const bf16x8*)(sB + (wn * 64 + j * 16 + r) * 32 + q * 8);
#pragma unroll
    for (int i = 0; i < 4; i++)
#pragma unroll
      for (int j = 0; j < 4; j++)
        acc[i][j] = __builtin_amdgcn_mfma_f32_16x16x32_bf16(a[i], bb[j], acc[i][j], 0, 0, 0);
    __syncthreads();
  }
#pragma unroll
  for (int i = 0; i < 4; i++)
#pragma unroll
    for (int j = 0; j < 4; j++)
#pragma unroll
      for (int rr = 0; rr < 4; rr++) {
        int ent = m0 + wm * 64 + i * 16 + q * 4 + rr;
        if (ent < ne) {
          int col = n0 + wn * 64 + j * 16 + r;
          hbuf[(size_t)(base + ent) * H_DIM + col] = f2bf(silu_f(acc[i][j][rr]));
        }
      }
}

// ---------------- M2: moe = h @ w2[e]^T, dense per-slot stores (NO atomics) ----------------
__global__ __launch_bounds__(256) void k_moe2(
    const uint16_t* __restrict__ hbuf, const uint16_t* __restrict__ w2b,
    const int* __restrict__ offsets, const float* __restrict__ slot_w,
    float* __restrict__ slot_out) {
  const int e = blockIdx.z;
  const int base = offsets[e];
  const int ne = offsets[e + 1] - base;
  const int m0 = blockIdx.x * 128;
  if (m0 >= ne) return;
  const int n0 = blockIdx.y * 128;  // over D=1024
  __shared__ uint16_t sA[128 * 32], sB[128 * 32];
  const int tid = threadIdx.x, lane = tid & 63, wid = tid >> 6;
  const int wm = wid >> 1, wn = wid & 1;
  f32x4 acc[4][4];
#pragma unroll
  for (int i = 0; i < 4; i++)
#pragma unroll
    for (int j = 0; j < 4; j++) acc[i][j] = (f32x4){0.f, 0.f, 0.f, 0.f};

  const int row0 = tid >> 2, col8 = (tid & 3) * 8;
  const int e0 = min(m0 + row0, ne - 1);
  const int e1 = min(m0 + row0 + 64, ne - 1);
  const uint16_t* ga0 = hbuf + (size_t)(base + e0) * H_DIM + col8;
  const uint16_t* ga1 = hbuf + (size_t)(base + e1) * H_DIM + col8;
  const uint16_t* wbase = w2b + (size_t)e * D_DIM * H_DIM;
  const uint16_t* gb0 = wbase + (size_t)(n0 + row0) * H_DIM + col8;
  const uint16_t* gb1 = gb0 + 64 * H_DIM;
  uint16_t* lA0 = sA + wid * 512; uint16_t* lA1 = sA + 2048 + wid * 512;
  uint16_t* lB0 = sB + wid * 512; uint16_t* lB1 = sB + 2048 + wid * 512;
  const int r = lane & 15, q = lane >> 4;
  for (int kt = 0; kt < H_DIM; kt += 32) {
    gl_lds16(ga0, lA0); gl_lds16(ga1, lA1);
    gl_lds16(gb0, lB0); gl_lds16(gb1, lB1);
    ga0 += 32; ga1 += 32; gb0 += 32; gb1 += 32;
    __syncthreads();
    bf16x8 a[4], bb[4];
#pragma unroll
    for (int i = 0; i < 4; i++)
      a[i] = *(const bf16x8*)(sA + (wm * 64 + i * 16 + r) * 32 + q * 8);
#pragma unroll
    for (int j = 0; j < 4; j++)
      bb[j] = *(const bf16x8*)(sB + (wn * 64 + j * 16 + r) * 32 + q * 8);
#pragma unroll
    for (int i = 0; i < 4; i++)
#pragma unroll
      for (int j = 0; j < 4; j++)
        acc[i][j] = __builtin_amdgcn_mfma_f32_16x16x32_bf16(a[i], bb[j], acc[i][j], 0, 0, 0);
    __syncthreads();
  }
#pragma unroll
  for (int i = 0; i < 4; i++) {
    int ent_base = m0 + wm * 64 + i * 16 + q * 4;
#pragma unroll
    for (int rr = 0; rr < 4; rr++) {
      int ent = ent_base + rr;
      if (ent < ne) {
        float w = slot_w[base + ent];
        float* orow = slot_out + (size_t)(base + ent) * D_DIM;
#pragma unroll
        for (int j = 0; j < 4; j++) {
          int col = n0 + wn * 64 + j * 16 + r;
          orow[col] = w * acc[i][j][rr];
        }
      }
    }
  }
}

// ---------------- combine: out[t] += slot_out[slot0[t]] + slot_out[slot1[t]] ----------------
__global__ __launch_bounds__(256) void k_combine(
    const float* __restrict__ slot_out, const int* __restrict__ slot_of,
    float* __restrict__ out) {
  int t = blockIdx.x;
  int c = threadIdx.x;
  int s0 = slot_of[t * 2], s1 = slot_of[t * 2 + 1];
  float4 a = ((const float4*)(slot_out + (size_t)s0 * D_DIM))[c];
  float4 b = ((const float4*)(slot_out + (size_t)s1 * D_DIM))[c];
  float4* po = (float4*)(out + (size_t)t * D_DIM) + c;
  float4 o = *po;
  o.x += a.x + b.x; o.y += a.y + b.y; o.z += a.z + b.z; o.w += a.w + b.w;
  *po = o;
}

// ---------------- launch ----------------
extern "C" void kernel_launch(void* const* d_in, const int* in_sizes, int n_in,
                              void* d_out, int out_size, void* d_ws, size_t ws_size,
                              hipStream_t stream) {
  const float* x     = (const float*)d_in[0];
  const float* gatew = (const float*)d_in[1];
  const float* w1    = (const float*)d_in[2];
  const float* w2    = (const float*)d_in[3];
  const float* sfc1  = (const float*)d_in[4];
  const float* sfc2  = (const float*)d_in[5];
  const float* sfc3  = (const float*)d_in[6];
  float* out = (float*)d_out;

  uint8_t* ws = (uint8_t*)d_ws;
  size_t off = 0;
  auto alloc = [&](size_t bytes) {
    void* p = ws + off;
    off = (off + bytes + 255) & ~(size_t)255;
    return p;
  };
  uint16_t* xb    = (uint16_t*)alloc((size_t)T_TOK * D_DIM * 2);
  uint16_t* sfc1b = (uint16_t*)alloc((size_t)S_DIM * D_DIM * 2);
  uint16_t* sfc2b = (uint16_t*)alloc((size_t)S_DIM * D_DIM * 2);
  uint16_t* sfc3b = (uint16_t*)alloc((size_t)D_DIM * S_DIM * 2);
  uint16_t* w1b   = (uint16_t*)alloc((size_t)E_NUM * H_DIM * D_DIM * 2);
  uint16_t* w2b   = (uint16_t*)alloc((size_t)E_NUM * D_DIM * H_DIM * 2);
  uint16_t* hsb   = (uint16_t*)alloc((size_t)T_TOK * S_DIM * 2);
  uint16_t* hbuf  = (uint16_t*)alloc((size_t)2 * T_TOK * H_DIM * 2);
  float* slot_out = (float*)alloc((size_t)2 * T_TOK * D_DIM * 4);
  float4* gwT4    = (float4*)alloc((size_t)D_DIM / 4 * E_NUM * 16);
  int*   top_idx  = (int*)alloc((size_t)T_TOK * 2 * 4);
  float* top_w    = (float*)alloc((size_t)T_TOK * 2 * 4);
  int*   partial  = (int*)alloc(32 * E_NUM * 4);
  int*   bases    = (int*)alloc(32 * E_NUM * 4);
  int*   offsets  = (int*)alloc((E_NUM + 1) * 4);
  int*   slot_token = (int*)alloc((size_t)2 * T_TOK * 4);
  float* slot_w   = (float*)alloc((size_t)2 * T_TOK * 4);
  int*   slot_of  = (int*)alloc((size_t)2 * T_TOK * 4);

  // 1. casts + gw transpose
  {
    int n4;
    n4 = T_TOK * D_DIM / 4;  k_cast<<<(n4 + 255) / 256, 256, 0, stream>>>(x, xb, n4);
    n4 = S_DIM * D_DIM / 4;  k_cast<<<(n4 + 255) / 256, 256, 0, stream>>>(sfc1, sfc1b, n4);
    n4 = S_DIM * D_DIM / 4;  k_cast<<<(n4 + 255) / 256, 256, 0, stream>>>(sfc2, sfc2b, n4);
    n4 = D_DIM * S_DIM / 4;  k_cast<<<(n4 + 255) / 256, 256, 0, stream>>>(sfc3, sfc3b, n4);
    n4 = E_NUM * H_DIM * D_DIM / 4; k_cast<<<(n4 + 255) / 256, 256, 0, stream>>>(w1, w1b, n4);
    n4 = E_NUM * D_DIM * H_DIM / 4; k_cast<<<(n4 + 255) / 256, 256, 0, stream>>>(w2, w2b, n4);
    k_gwT<<<(E_NUM * D_DIM / 4 + 255) / 256, 256, 0, stream>>>(gatew, gwT4);
  }
  // 2. router + counting sort (no contended global atomics anywhere)
  k_router<<<T_TOK / 4, 256, 0, stream>>>(x, gwT4, top_idx, top_w);
  k_hist<<<32, 256, 0, stream>>>(top_idx, partial);
  k_scan<<<1, 64, 0, stream>>>(partial, bases, offsets);
  k_scatter<<<32, 256, 0, stream>>>(top_idx, top_w, bases, slot_token, slot_w, slot_of);
  // 3. shared expert
  k_dual_gemm_silu<<<dim3(T_TOK / 128, S_DIM / 128), 256, 0, stream>>>(xb, sfc1b, sfc2b, hsb);
  k_gemm_shared_out<<<dim3(T_TOK / 128, D_DIM / 128), 256, 0, stream>>>(hsb, sfc3b, out);
  // 4. MoE grouped
  k_moe1<<<dim3(T_TOK / 128, H_DIM / 128, E_NUM), 256, 0, stream>>>(xb, w1b, offsets, slot_token, hbuf);
  k_moe2<<<dim3(T_TOK / 128, D_DIM / 128, E_NUM), 256, 0, stream>>>(hbuf, w2b, offsets, slot_w, slot_out);
  // 5. combine MoE slots into output
  k_combine<<<T_TOK, 256, 0, stream>>>(slot_out, slot_of, out);
}

// Round 5
// 477.913 us; speedup vs baseline: 1.2420x; 1.0150x over previous
//
#include <hip/hip_runtime.h>
#include <stdint.h>

// Problem constants (B=2, L=2048 -> T=4096)
#define T_TOK 4096
#define D_DIM 1024
#define H_DIM 512
#define E_NUM 16
#define S_DIM 2048

typedef __attribute__((ext_vector_type(8))) __bf16 bf16x8;
typedef __attribute__((ext_vector_type(4))) float f32x4;

__device__ __forceinline__ uint16_t f2bf(float f) {
  uint32_t u = __float_as_uint(f);
  u += 0x7fffu + ((u >> 16) & 1u);   // round-to-nearest-even
  return (uint16_t)(u >> 16);
}

__device__ __forceinline__ float bf2f(uint16_t u) {
  return __uint_as_float(((uint32_t)u) << 16);
}

__device__ __forceinline__ void gl_lds16(const void* g, void* l) {
  __builtin_amdgcn_global_load_lds(
      (const __attribute__((address_space(1))) void*)g,
      (__attribute__((address_space(3))) void*)l, 16, 0, 0);
}

__device__ __forceinline__ float silu_f(float v) {
  return v / (1.f + __expf(-v));
}

// ---------------- fp32 -> bf16 cast ----------------
__global__ void k_cast(const float* __restrict__ in, uint16_t* __restrict__ out, int n4) {
  int i = blockIdx.x * 256 + threadIdx.x;
  if (i >= n4) return;
  float4 v = ((const float4*)in)[i];
  ushort4 o;
  o.x = f2bf(v.x); o.y = f2bf(v.y); o.z = f2bf(v.z); o.w = f2bf(v.w);
  ((ushort4*)out)[i] = o;
}

// ---------------- gw transpose: [E][D] -> [D/4][E] of float4 ----------------
__global__ void k_gwT(const float* __restrict__ gw, float4* __restrict__ gwT4) {
  int tid = blockIdx.x * 256 + threadIdx.x;  // 4096 threads
  if (tid >= E_NUM * (D_DIM / 4)) return;
  int k4 = tid & (D_DIM / 4 - 1);
  int e = tid >> 8;
  float4 v = ((const float4*)(gw + (size_t)e * D_DIM))[k4];
  gwT4[(size_t)k4 * E_NUM + e] = v;
}

// ---------------- router: fp32 logits, in-register top-2, NO atomics ----------------
__global__ __launch_bounds__(256) void k_router(
    const float* __restrict__ x, const float4* __restrict__ gwT4,
    int* __restrict__ top_idx, float* __restrict__ top_w) {
  const int wid = threadIdx.x >> 6, lane = threadIdx.x & 63;
  const int t = blockIdx.x * 4 + wid;
  const int e = lane & 15, q = lane >> 4;
  const float4* xr4 = (const float4*)(x + (size_t)t * D_DIM) + q * 64;
  const float4* g4 = gwT4 + (size_t)q * 64 * E_NUM + e;
  float acc = 0.f;
#pragma unroll 8
  for (int i = 0; i < 64; i++) {
    float4 xv = xr4[i];
    float4 gv = g4[(size_t)i * E_NUM];
    acc += xv.x * gv.x + xv.y * gv.y + xv.z * gv.z + xv.w * gv.w;
  }
  acc += __shfl_xor(acc, 16, 64);
  acc += __shfl_xor(acc, 32, 64);
  float v1 = acc; int i1 = e;
#pragma unroll
  for (int off = 1; off < 16; off <<= 1) {
    float ov = __shfl_xor(v1, off, 64);
    int oi = __shfl_xor(i1, off, 64);
    if (ov > v1 || (ov == v1 && oi < i1)) { v1 = ov; i1 = oi; }
  }
  float v2 = (e == i1) ? -1e30f : acc; int i2 = e;
#pragma unroll
  for (int off = 1; off < 16; off <<= 1) {
    float ov = __shfl_xor(v2, off, 64);
    int oi = __shfl_xor(i2, off, 64);
    if (ov > v2 || (ov == v2 && oi < i2)) { v2 = ov; i2 = oi; }
  }
  if (lane == 0) {
    float w0 = 1.f / (1.f + __expf(v2 - v1));
    top_idx[t * 2] = i1; top_idx[t * 2 + 1] = i2;
    top_w[t * 2] = w0;  top_w[t * 2 + 1] = 1.f - w0;
  }
}

// ---------------- counting sort (no global atomics) ----------------
__global__ __launch_bounds__(256) void k_hist(const int* __restrict__ top_idx,
                                              int* __restrict__ partial) {
  __shared__ int h[E_NUM];
  int tid = threadIdx.x;
  if (tid < E_NUM) h[tid] = 0;
  __syncthreads();
  int id = blockIdx.x * 256 + tid;
  atomicAdd(&h[top_idx[id]], 1);
  __syncthreads();
  if (tid < E_NUM) partial[blockIdx.x * E_NUM + tid] = h[tid];
}

__global__ void k_scan(const int* __restrict__ partial, int* __restrict__ bases,
                       int* __restrict__ offsets) {
  __shared__ int tot[E_NUM];
  int e = threadIdx.x;
  if (e < E_NUM) {
    int run = 0;
    for (int b = 0; b < 32; b++) { bases[b * E_NUM + e] = run; run += partial[b * E_NUM + e]; }
    tot[e] = run;
  }
  __syncthreads();
  if (e == 0) {
    int s = 0;
    for (int i = 0; i < E_NUM; i++) { offsets[i] = s; s += tot[i]; }
    offsets[E_NUM] = s;
  }
  __syncthreads();
  if (e < E_NUM) {
    int off = offsets[e];
    for (int b = 0; b < 32; b++) bases[b * E_NUM + e] += off;
  }
}

__global__ __launch_bounds__(256) void k_scatter(
    const int* __restrict__ top_idx, const float* __restrict__ top_w,
    const int* __restrict__ bases, int* __restrict__ slot_token,
    float* __restrict__ slot_w, int* __restrict__ slot_of) {
  __shared__ int cur[E_NUM];
  int tid = threadIdx.x;
  if (tid < E_NUM) cur[tid] = bases[blockIdx.x * E_NUM + tid];
  __syncthreads();
  int id = blockIdx.x * 256 + tid;
  int e = top_idx[id];
  int slot = atomicAdd(&cur[e], 1);   // LDS atomic — cheap
  slot_token[slot] = id >> 1;
  slot_w[slot] = top_w[id];
  slot_of[id] = slot;
}

// ---------------- GEMM cores: double-buffered LDS pipeline ----------------
// LDS tiles: [128 rows][32 cols] bf16, K-contiguous, x2 buffers. Stage tile
// k+1 via global_load_lds while MFMA-ing tile k; ONE barrier per iteration
// (its vmcnt(0) drain is what completes the prefetch).

// ---------------- G1: dual GEMM, epilogue silu(a1)*a2 -> Hs bf16 ----------------
__global__ __launch_bounds__(256) void k_dual_gemm_silu(
    const uint16_t* __restrict__ xb, const uint16_t* __restrict__ b1,
    const uint16_t* __restrict__ b2, uint16_t* __restrict__ hs) {
  __shared__ uint16_t sA[2 * 4096], sB1[2 * 4096], sB2[2 * 4096];
  const int tid = threadIdx.x, lane = tid & 63, wid = tid >> 6;
  const int wm = wid >> 1, wn = wid & 1;
  const int bm0 = blockIdx.x * 128, bn0 = blockIdx.y * 128;

  f32x4 acc1[4][4], acc2[4][4];
#pragma unroll
  for (int i = 0; i < 4; i++)
#pragma unroll
    for (int j = 0; j < 4; j++) {
      acc1[i][j] = (f32x4){0.f, 0.f, 0.f, 0.f};
      acc2[i][j] = (f32x4){0.f, 0.f, 0.f, 0.f};
    }

  const int row0 = tid >> 2, col8 = (tid & 3) * 8;
  const uint16_t* ga0 = xb + (size_t)(bm0 + row0) * D_DIM + col8;
  const uint16_t* ga1 = ga0 + 64 * D_DIM;
  const uint16_t* gb10 = b1 + (size_t)(bn0 + row0) * D_DIM + col8;
  const uint16_t* gb11 = gb10 + 64 * D_DIM;
  const uint16_t* gb20 = b2 + (size_t)(bn0 + row0) * D_DIM + col8;
  const uint16_t* gb21 = gb20 + 64 * D_DIM;
  const int r = lane & 15, q = lane >> 4;

  auto stage = [&](int buf) {
    uint16_t* A = sA + buf * 4096;
    uint16_t* B1 = sB1 + buf * 4096;
    uint16_t* B2 = sB2 + buf * 4096;
    gl_lds16(ga0, A + wid * 512);   gl_lds16(ga1, A + 2048 + wid * 512);
    gl_lds16(gb10, B1 + wid * 512); gl_lds16(gb11, B1 + 2048 + wid * 512);
    gl_lds16(gb20, B2 + wid * 512); gl_lds16(gb21, B2 + 2048 + wid * 512);
    ga0 += 32; ga1 += 32; gb10 += 32; gb11 += 32; gb20 += 32; gb21 += 32;
  };
  auto compute = [&](int buf) {
    const uint16_t* A = sA + buf * 4096;
    const uint16_t* B1 = sB1 + buf * 4096;
    const uint16_t* B2 = sB2 + buf * 4096;
    bf16x8 a[4];
#pragma unroll
    for (int i = 0; i < 4; i++)
      a[i] = *(const bf16x8*)(A + (wm * 64 + i * 16 + r) * 32 + q * 8);
#pragma unroll
    for (int j = 0; j < 4; j++) {
      bf16x8 b = *(const bf16x8*)(B1 + (wn * 64 + j * 16 + r) * 32 + q * 8);
#pragma unroll
      for (int i = 0; i < 4; i++)
        acc1[i][j] = __builtin_amdgcn_mfma_f32_16x16x32_bf16(a[i], b, acc1[i][j], 0, 0, 0);
    }
#pragma unroll
    for (int j = 0; j < 4; j++) {
      bf16x8 b = *(const bf16x8*)(B2 + (wn * 64 + j * 16 + r) * 32 + q * 8);
#pragma unroll
      for (int i = 0; i < 4; i++)
        acc2[i][j] = __builtin_amdgcn_mfma_f32_16x16x32_bf16(a[i], b, acc2[i][j], 0, 0, 0);
    }
  };

  stage(0);
  __syncthreads();
  int cur = 0;
  for (int kt = 32; kt < D_DIM; kt += 32) {
    stage(cur ^ 1);
    compute(cur);
    __syncthreads();
    cur ^= 1;
  }
  compute(cur);

#pragma unroll
  for (int i = 0; i < 4; i++)
#pragma unroll
    for (int j = 0; j < 4; j++)
#pragma unroll
      for (int rr = 0; rr < 4; rr++) {
        int row = bm0 + wm * 64 + i * 16 + q * 4 + rr;
        int col = bn0 + wn * 64 + j * 16 + r;
        float aa = acc1[i][j][rr], bb = acc2[i][j][rr];
        hs[(size_t)row * S_DIM + col] = f2bf(silu_f(aa) * bb);
      }
}

// ---------------- G2: shared = Hs @ sfc3^T -> fp32 stores to out ----------------
__global__ __launch_bounds__(256) void k_gemm_shared_out(
    const uint16_t* __restrict__ hsb, const uint16_t* __restrict__ b,
    float* __restrict__ out) {
  __shared__ uint16_t sA[2 * 4096], sB[2 * 4096];
  const int tid = threadIdx.x, lane = tid & 63, wid = tid >> 6;
  const int wm = wid >> 1, wn = wid & 1;
  const int bm0 = blockIdx.x * 128, bn0 = blockIdx.y * 128;
  f32x4 acc[4][4];
#pragma unroll
  for (int i = 0; i < 4; i++)
#pragma unroll
    for (int j = 0; j < 4; j++) acc[i][j] = (f32x4){0.f, 0.f, 0.f, 0.f};

  const int row0 = tid >> 2, col8 = (tid & 3) * 8;
  const uint16_t* ga0 = hsb + (size_t)(bm0 + row0) * S_DIM + col8;
  const uint16_t* ga1 = ga0 + (size_t)64 * S_DIM;
  const uint16_t* gb0 = b + (size_t)(bn0 + row0) * S_DIM + col8;
  const uint16_t* gb1 = gb0 + (size_t)64 * S_DIM;
  const int r = lane & 15, q = lane >> 4;

  auto stage = [&](int buf) {
    uint16_t* A = sA + buf * 4096;
    uint16_t* B = sB + buf * 4096;
    gl_lds16(ga0, A + wid * 512); gl_lds16(ga1, A + 2048 + wid * 512);
    gl_lds16(gb0, B + wid * 512); gl_lds16(gb1, B + 2048 + wid * 512);
    ga0 += 32; ga1 += 32; gb0 += 32; gb1 += 32;
  };
  auto compute = [&](int buf) {
    const uint16_t* A = sA + buf * 4096;
    const uint16_t* B = sB + buf * 4096;
    bf16x8 a[4], bb[4];
#pragma unroll
    for (int i = 0; i < 4; i++)
      a[i] = *(const bf16x8*)(A + (wm * 64 + i * 16 + r) * 32 + q * 8);
#pragma unroll
    for (int j = 0; j < 4; j++)
      bb[j] = *(const bf16x8*)(B + (wn * 64 + j * 16 + r) * 32 + q * 8);
#pragma unroll
    for (int i = 0; i < 4; i++)
#pragma unroll
      for (int j = 0; j < 4; j++)
        acc[i][j] = __builtin_amdgcn_mfma_f32_16x16x32_bf16(a[i], bb[j], acc[i][j], 0, 0, 0);
  };

  stage(0);
  __syncthreads();
  int cur = 0;
  for (int kt = 32; kt < S_DIM; kt += 32) {
    stage(cur ^ 1);
    compute(cur);
    __syncthreads();
    cur ^= 1;
  }
  compute(cur);

#pragma unroll
  for (int i = 0; i < 4; i++)
#pragma unroll
    for (int j = 0; j < 4; j++)
#pragma unroll
      for (int rr = 0; rr < 4; rr++) {
        int row = bm0 + wm * 64 + i * 16 + q * 4 + rr;
        int col = bn0 + wn * 64 + j * 16 + r;
        out[(size_t)row * D_DIM + col] = acc[i][j][rr];
      }
}

// ---------------- M1: grouped h = silu(Xg @ w1[e]^T) -> bf16 ----------------
__global__ __launch_bounds__(256) void k_moe1(
    const uint16_t* __restrict__ xb, const uint16_t* __restrict__ w1b,
    const int* __restrict__ offsets, const int* __restrict__ slot_token,
    uint16_t* __restrict__ hbuf) {
  const int e = blockIdx.z;
  const int base = offsets[e];
  const int ne = offsets[e + 1] - base;
  const int m0 = blockIdx.x * 128;
  if (m0 >= ne) return;
  const int n0 = blockIdx.y * 128;  // over H=512
  __shared__ uint16_t sA[2 * 4096], sB[2 * 4096];
  const int tid = threadIdx.x, lane = tid & 63, wid = tid >> 6;
  const int wm = wid >> 1, wn = wid & 1;
  f32x4 acc[4][4];
#pragma unroll
  for (int i = 0; i < 4; i++)
#pragma unroll
    for (int j = 0; j < 4; j++) acc[i][j] = (f32x4){0.f, 0.f, 0.f, 0.f};

  const int row0 = tid >> 2, col8 = (tid & 3) * 8;
  const int e0 = min(m0 + row0, ne - 1);
  const int e1 = min(m0 + row0 + 64, ne - 1);
  const uint16_t* ga0 = xb + (size_t)slot_token[base + e0] * D_DIM + col8;
  const uint16_t* ga1 = xb + (size_t)slot_token[base + e1] * D_DIM + col8;
  const uint16_t* wbase = w1b + (size_t)e * H_DIM * D_DIM;
  const uint16_t* gb0 = wbase + (size_t)(n0 + row0) * D_DIM + col8;
  const uint16_t* gb1 = gb0 + 64 * D_DIM;
  const int r = lane & 15, q = lane >> 4;

  auto stage = [&](int buf) {
    uint16_t* A = sA + buf * 4096;
    uint16_t* B = sB + buf * 4096;
    gl_lds16(ga0, A + wid * 512); gl_lds16(ga1, A + 2048 + wid * 512);
    gl_lds16(gb0, B + wid * 512); gl_lds16(gb1, B + 2048 + wid * 512);
    ga0 += 32; ga1 += 32; gb0 += 32; gb1 += 32;
  };
  auto compute = [&](int buf) {
    const uint16_t* A = sA + buf * 4096;
    const uint16_t* B = sB + buf * 4096;
    bf16x8 a[4], bb[4];
#pragma unroll
    for (int i = 0; i < 4; i++)
      a[i] = *(const bf16x8*)(A + (wm * 64 + i * 16 + r) * 32 + q * 8);
#pragma unroll
    for (int j = 0; j < 4; j++)
      bb[j] = *(const bf16x8*)(B + (wn * 64 + j * 16 + r) * 32 + q * 8);
#pragma unroll
    for (int i = 0; i < 4; i++)
#pragma unroll
      for (int j = 0; j < 4; j++)
        acc[i][j] = __builtin_amdgcn_mfma_f32_16x16x32_bf16(a[i], bb[j], acc[i][j], 0, 0, 0);
  };

  stage(0);
  __syncthreads();
  int cur = 0;
  for (int kt = 32; kt < D_DIM; kt += 32) {
    stage(cur ^ 1);
    compute(cur);
    __syncthreads();
    cur ^= 1;
  }
  compute(cur);

#pragma unroll
  for (int i = 0; i < 4; i++)
#pragma unroll
    for (int j = 0; j < 4; j++)
#pragma unroll
      for (int rr = 0; rr < 4; rr++) {
        int ent = m0 + wm * 64 + i * 16 + q * 4 + rr;
        if (ent < ne) {
          int col = n0 + wn * 64 + j * 16 + r;
          hbuf[(size_t)(base + ent) * H_DIM + col] = f2bf(silu_f(acc[i][j][rr]));
        }
      }
}

// ---------------- M2: moe = h @ w2[e]^T, bf16 per-slot stores ----------------
__global__ __launch_bounds__(256) void k_moe2(
    const uint16_t* __restrict__ hbuf, const uint16_t* __restrict__ w2b,
    const int* __restrict__ offsets, const float* __restrict__ slot_w,
    uint16_t* __restrict__ slot_out) {
  const int e = blockIdx.z;
  const int base = offsets[e];
  const int ne = offsets[e + 1] - base;
  const int m0 = blockIdx.x * 128;
  if (m0 >= ne) return;
  const int n0 = blockIdx.y * 128;  // over D=1024
  __shared__ uint16_t sA[2 * 4096], sB[2 * 4096];
  const int tid = threadIdx.x, lane = tid & 63, wid = tid >> 6;
  const int wm = wid >> 1, wn = wid & 1;
  f32x4 acc[4][4];
#pragma unroll
  for (int i = 0; i < 4; i++)
#pragma unroll
    for (int j = 0; j < 4; j++) acc[i][j] = (f32x4){0.f, 0.f, 0.f, 0.f};

  const int row0 = tid >> 2, col8 = (tid & 3) * 8;
  const int e0 = min(m0 + row0, ne - 1);
  const int e1 = min(m0 + row0 + 64, ne - 1);
  const uint16_t* ga0 = hbuf + (size_t)(base + e0) * H_DIM + col8;
  const uint16_t* ga1 = hbuf + (size_t)(base + e1) * H_DIM + col8;
  const uint16_t* wbase = w2b + (size_t)e * D_DIM * H_DIM;
  const uint16_t* gb0 = wbase + (size_t)(n0 + row0) * H_DIM + col8;
  const uint16_t* gb1 = gb0 + 64 * H_DIM;
  const int r = lane & 15, q = lane >> 4;

  auto stage = [&](int buf) {
    uint16_t* A = sA + buf * 4096;
    uint16_t* B = sB + buf * 4096;
    gl_lds16(ga0, A + wid * 512); gl_lds16(ga1, A + 2048 + wid * 512);
    gl_lds16(gb0, B + wid * 512); gl_lds16(gb1, B + 2048 + wid * 512);
    ga0 += 32; ga1 += 32; gb0 += 32; gb1 += 32;
  };
  auto compute = [&](int buf) {
    const uint16_t* A = sA + buf * 4096;
    const uint16_t* B = sB + buf * 4096;
    bf16x8 a[4], bb[4];
#pragma unroll
    for (int i = 0; i < 4; i++)
      a[i] = *(const bf16x8*)(A + (wm * 64 + i * 16 + r) * 32 + q * 8);
#pragma unroll
    for (int j = 0; j < 4; j++)
      bb[j] = *(const bf16x8*)(B + (wn * 64 + j * 16 + r) * 32 + q * 8);
#pragma unroll
    for (int i = 0; i < 4; i++)
#pragma unroll
      for (int j = 0; j < 4; j++)
        acc[i][j] = __builtin_amdgcn_mfma_f32_16x16x32_bf16(a[i], bb[j], acc[i][j], 0, 0, 0);
  };

  stage(0);
  __syncthreads();
  int cur = 0;
  for (int kt = 32; kt < H_DIM; kt += 32) {
    stage(cur ^ 1);
    compute(cur);
    __syncthreads();
    cur ^= 1;
  }
  compute(cur);

#pragma unroll
  for (int i = 0; i < 4; i++) {
    int ent_base = m0 + wm * 64 + i * 16 + q * 4;
#pragma unroll
    for (int rr = 0; rr < 4; rr++) {
      int ent = ent_base + rr;
      if (ent < ne) {
        float w = slot_w[base + ent];
        uint16_t* orow = slot_out + (size_t)(base + ent) * D_DIM;
#pragma unroll
        for (int j = 0; j < 4; j++) {
          int col = n0 + wn * 64 + j * 16 + r;
          orow[col] = f2bf(w * acc[i][j][rr]);
        }
      }
    }
  }
}

// ---------------- combine: out[t] += slot_out[s0] + slot_out[s1] (bf16 in) ----------------
__global__ __launch_bounds__(256) void k_combine(
    const uint16_t* __restrict__ slot_out, const int* __restrict__ slot_of,
    float* __restrict__ out) {
  int t = blockIdx.x;
  int c = threadIdx.x;
  int s0 = slot_of[t * 2], s1 = slot_of[t * 2 + 1];
  ushort4 a = ((const ushort4*)(slot_out + (size_t)s0 * D_DIM))[c];
  ushort4 b = ((const ushort4*)(slot_out + (size_t)s1 * D_DIM))[c];
  float4* po = (float4*)(out + (size_t)t * D_DIM) + c;
  float4 o = *po;
  o.x += bf2f(a.x) + bf2f(b.x);
  o.y += bf2f(a.y) + bf2f(b.y);
  o.z += bf2f(a.z) + bf2f(b.z);
  o.w += bf2f(a.w) + bf2f(b.w);
  *po = o;
}

// ---------------- launch ----------------
extern "C" void kernel_launch(void* const* d_in, const int* in_sizes, int n_in,
                              void* d_out, int out_size, void* d_ws, size_t ws_size,
                              hipStream_t stream) {
  const float* x     = (const float*)d_in[0];
  const float* gatew = (const float*)d_in[1];
  const float* w1    = (const float*)d_in[2];
  const float* w2    = (const float*)d_in[3];
  const float* sfc1  = (const float*)d_in[4];
  const float* sfc2  = (const float*)d_in[5];
  const float* sfc3  = (const float*)d_in[6];
  float* out = (float*)d_out;

  uint8_t* ws = (uint8_t*)d_ws;
  size_t off = 0;
  auto alloc = [&](size_t bytes) {
    void* p = ws + off;
    off = (off + bytes + 255) & ~(size_t)255;
    return p;
  };
  uint16_t* xb    = (uint16_t*)alloc((size_t)T_TOK * D_DIM * 2);
  uint16_t* sfc1b = (uint16_t*)alloc((size_t)S_DIM * D_DIM * 2);
  uint16_t* sfc2b = (uint16_t*)alloc((size_t)S_DIM * D_DIM * 2);
  uint16_t* sfc3b = (uint16_t*)alloc((size_t)D_DIM * S_DIM * 2);
  uint16_t* w1b   = (uint16_t*)alloc((size_t)E_NUM * H_DIM * D_DIM * 2);
  uint16_t* w2b   = (uint16_t*)alloc((size_t)E_NUM * D_DIM * H_DIM * 2);
  uint16_t* hsb   = (uint16_t*)alloc((size_t)T_TOK * S_DIM * 2);
  uint16_t* hbuf  = (uint16_t*)alloc((size_t)2 * T_TOK * H_DIM * 2);
  uint16_t* slot_out = (uint16_t*)alloc((size_t)2 * T_TOK * D_DIM * 2);
  float4* gwT4    = (float4*)alloc((size_t)D_DIM / 4 * E_NUM * 16);
  int*   top_idx  = (int*)alloc((size_t)T_TOK * 2 * 4);
  float* top_w    = (float*)alloc((size_t)T_TOK * 2 * 4);
  int*   partial  = (int*)alloc(32 * E_NUM * 4);
  int*   bases    = (int*)alloc(32 * E_NUM * 4);
  int*   offsets  = (int*)alloc((E_NUM + 1) * 4);
  int*   slot_token = (int*)alloc((size_t)2 * T_TOK * 4);
  float* slot_w   = (float*)alloc((size_t)2 * T_TOK * 4);
  int*   slot_of  = (int*)alloc((size_t)2 * T_TOK * 4);

  // 1. casts + gw transpose
  {
    int n4;
    n4 = T_TOK * D_DIM / 4;  k_cast<<<(n4 + 255) / 256, 256, 0, stream>>>(x, xb, n4);
    n4 = S_DIM * D_DIM / 4;  k_cast<<<(n4 + 255) / 256, 256, 0, stream>>>(sfc1, sfc1b, n4);
    n4 = S_DIM * D_DIM / 4;  k_cast<<<(n4 + 255) / 256, 256, 0, stream>>>(sfc2, sfc2b, n4);
    n4 = D_DIM * S_DIM / 4;  k_cast<<<(n4 + 255) / 256, 256, 0, stream>>>(sfc3, sfc3b, n4);
    n4 = E_NUM * H_DIM * D_DIM / 4; k_cast<<<(n4 + 255) / 256, 256, 0, stream>>>(w1, w1b, n4);
    n4 = E_NUM * D_DIM * H_DIM / 4; k_cast<<<(n4 + 255) / 256, 256, 0, stream>>>(w2, w2b, n4);
    k_gwT<<<(E_NUM * D_DIM / 4 + 255) / 256, 256, 0, stream>>>(gatew, gwT4);
  }
  // 2. router + counting sort (no contended global atomics anywhere)
  k_router<<<T_TOK / 4, 256, 0, stream>>>(x, gwT4, top_idx, top_w);
  k_hist<<<32, 256, 0, stream>>>(top_idx, partial);
  k_scan<<<1, 64, 0, stream>>>(partial, bases, offsets);
  k_scatter<<<32, 256, 0, stream>>>(top_idx, top_w, bases, slot_token, slot_w, slot_of);
  // 3. shared expert
  k_dual_gemm_silu<<<dim3(T_TOK / 128, S_DIM / 128), 256, 0, stream>>>(xb, sfc1b, sfc2b, hsb);
  k_gemm_shared_out<<<dim3(T_TOK / 128, D_DIM / 128), 256, 0, stream>>>(hsb, sfc3b, out);
  // 4. MoE grouped
  k_moe1<<<dim3(T_TOK / 128, H_DIM / 128, E_NUM), 256, 0, stream>>>(xb, w1b, offsets, slot_token, hbuf);
  k_moe2<<<dim3(T_TOK / 128, D_DIM / 128, E_NUM), 256, 0, stream>>>(hbuf, w2b, offsets, slot_w, slot_out);
  // 5. combine MoE slots into output
  k_combine<<<T_TOK, 256, 0, stream>>>(slot_out, slot_of, out);
}

// Round 6
// 349.489 us; speedup vs baseline: 1.6984x; 1.3675x over previous
//
#include <hip/hip_runtime.h>
#include <stdint.h>

// Problem constants (B=2, L=2048 -> T=4096)
#define T_TOK 4096
#define D_DIM 1024
#define H_DIM 512
#define E_NUM 16
#define S_DIM 2048

#define DUAL_BLOCKS 512   // (T/128) x (S/128) = 32 x 16
#define MOE1_TILES_MAX 80 // sum ceil(ne/128) <= 64 + 16
#define SHOUT_BLOCKS 256  // (T/128) x (D/128) = 32 x 8

typedef __attribute__((ext_vector_type(8))) __bf16 bf16x8;
typedef __attribute__((ext_vector_type(4))) float f32x4;

__device__ __forceinline__ uint16_t f2bf(float f) {
  uint32_t u = __float_as_uint(f);
  u += 0x7fffu + ((u >> 16) & 1u);   // round-to-nearest-even
  return (uint16_t)(u >> 16);
}

__device__ __forceinline__ float bf2f(uint16_t u) {
  return __uint_as_float(((uint32_t)u) << 16);
}

__device__ __forceinline__ void gl_lds16(const void* g, void* l) {
  __builtin_amdgcn_global_load_lds(
      (const __attribute__((address_space(1))) void*)g,
      (__attribute__((address_space(3))) void*)l, 16, 0, 0);
}

__device__ __forceinline__ float silu_f(float v) {
  return v / (1.f + __expf(-v));
}

// ---------------- fused fp32 -> bf16 cast of all six tensors ----------------
#define N4_X (T_TOK * D_DIM / 4)         // 1048576
#define N4_S (S_DIM * D_DIM / 4)         // 524288
#define N4_W (E_NUM * H_DIM * D_DIM / 4) // 2097152
#define N4_TOT (N4_X + 3 * N4_S + 2 * N4_W)

__global__ __launch_bounds__(256) void k_cast_all(
    const float* __restrict__ x, const float* __restrict__ sfc1,
    const float* __restrict__ sfc2, const float* __restrict__ sfc3,
    const float* __restrict__ w1, const float* __restrict__ w2,
    uint16_t* __restrict__ xb, uint16_t* __restrict__ s1b,
    uint16_t* __restrict__ s2b, uint16_t* __restrict__ s3b,
    uint16_t* __restrict__ w1b, uint16_t* __restrict__ w2b) {
  int i = blockIdx.x * 256 + threadIdx.x;
  if (i >= N4_TOT) return;
  const float* src; uint16_t* dst; int off;
  if (i < N4_X)                    { src = x;    dst = xb;  off = 0; }
  else if (i < N4_X + N4_S)        { src = sfc1; dst = s1b; off = N4_X; }
  else if (i < N4_X + 2 * N4_S)    { src = sfc2; dst = s2b; off = N4_X + N4_S; }
  else if (i < N4_X + 3 * N4_S)    { src = sfc3; dst = s3b; off = N4_X + 2 * N4_S; }
  else if (i < N4_X + 3 * N4_S + N4_W) { src = w1; dst = w1b; off = N4_X + 3 * N4_S; }
  else                             { src = w2;  dst = w2b; off = N4_X + 3 * N4_S + N4_W; }
  int j = i - off;
  float4 v = ((const float4*)src)[j];
  ushort4 o;
  o.x = f2bf(v.x); o.y = f2bf(v.y); o.z = f2bf(v.z); o.w = f2bf(v.w);
  ((ushort4*)dst)[j] = o;
}

// ---------------- gw transpose: [E][D] -> [D/4][E] of float4 ----------------
__global__ void k_gwT(const float* __restrict__ gw, float4* __restrict__ gwT4) {
  int tid = blockIdx.x * 256 + threadIdx.x;  // 4096 threads
  if (tid >= E_NUM * (D_DIM / 4)) return;
  int k4 = tid & (D_DIM / 4 - 1);
  int e = tid >> 8;
  float4 v = ((const float4*)(gw + (size_t)e * D_DIM))[k4];
  gwT4[(size_t)k4 * E_NUM + e] = v;
}

// ---------------- router: fp32 logits, in-register top-2, NO atomics ----------------
__global__ __launch_bounds__(256) void k_router(
    const float* __restrict__ x, const float4* __restrict__ gwT4,
    int* __restrict__ top_idx, float* __restrict__ top_w) {
  const int wid = threadIdx.x >> 6, lane = threadIdx.x & 63;
  const int t = blockIdx.x * 4 + wid;
  const int e = lane & 15, q = lane >> 4;
  const float4* xr4 = (const float4*)(x + (size_t)t * D_DIM) + q * 64;
  const float4* g4 = gwT4 + (size_t)q * 64 * E_NUM + e;
  float acc = 0.f;
#pragma unroll 8
  for (int i = 0; i < 64; i++) {
    float4 xv = xr4[i];
    float4 gv = g4[(size_t)i * E_NUM];
    acc += xv.x * gv.x + xv.y * gv.y + xv.z * gv.z + xv.w * gv.w;
  }
  acc += __shfl_xor(acc, 16, 64);
  acc += __shfl_xor(acc, 32, 64);
  float v1 = acc; int i1 = e;
#pragma unroll
  for (int off = 1; off < 16; off <<= 1) {
    float ov = __shfl_xor(v1, off, 64);
    int oi = __shfl_xor(i1, off, 64);
    if (ov > v1 || (ov == v1 && oi < i1)) { v1 = ov; i1 = oi; }
  }
  float v2 = (e == i1) ? -1e30f : acc; int i2 = e;
#pragma unroll
  for (int off = 1; off < 16; off <<= 1) {
    float ov = __shfl_xor(v2, off, 64);
    int oi = __shfl_xor(i2, off, 64);
    if (ov > v2 || (ov == v2 && oi < i2)) { v2 = ov; i2 = oi; }
  }
  if (lane == 0) {
    float w0 = 1.f / (1.f + __expf(v2 - v1));
    top_idx[t * 2] = i1; top_idx[t * 2 + 1] = i2;
    top_w[t * 2] = w0;  top_w[t * 2 + 1] = 1.f - w0;
  }
}

// ---------------- counting sort (no global atomics) ----------------
__global__ __launch_bounds__(256) void k_hist(const int* __restrict__ top_idx,
                                              int* __restrict__ partial) {
  __shared__ int h[E_NUM];
  int tid = threadIdx.x;
  if (tid < E_NUM) h[tid] = 0;
  __syncthreads();
  int id = blockIdx.x * 256 + tid;
  atomicAdd(&h[top_idx[id]], 1);
  __syncthreads();
  if (tid < E_NUM) partial[blockIdx.x * E_NUM + tid] = h[tid];
}

__global__ void k_scan(const int* __restrict__ partial, int* __restrict__ bases,
                       int* __restrict__ offsets, int* __restrict__ tile_e,
                       int* __restrict__ tile_m, int* __restrict__ tile_cnt) {
  __shared__ int tot[E_NUM];
  int e = threadIdx.x;
  if (e < E_NUM) {
    int run = 0;
    for (int b = 0; b < 32; b++) { bases[b * E_NUM + e] = run; run += partial[b * E_NUM + e]; }
    tot[e] = run;
  }
  __syncthreads();
  if (e == 0) {
    int s = 0;
    for (int i = 0; i < E_NUM; i++) { offsets[i] = s; s += tot[i]; }
    offsets[E_NUM] = s;
    // tile table for grouped MoE GEMMs
    int cnt = 0;
    for (int i = 0; i < E_NUM; i++) {
      for (int m0 = 0; m0 < tot[i]; m0 += 128) {
        tile_e[cnt] = i; tile_m[cnt] = m0; cnt++;
      }
    }
    tile_cnt[0] = cnt;
  }
  __syncthreads();
  if (e < E_NUM) {
    int off = offsets[e];
    for (int b = 0; b < 32; b++) bases[b * E_NUM + e] += off;
  }
}

__global__ __launch_bounds__(256) void k_scatter(
    const int* __restrict__ top_idx, const float* __restrict__ top_w,
    const int* __restrict__ bases, int* __restrict__ slot_token,
    float* __restrict__ slot_w, int* __restrict__ slot_of) {
  __shared__ int cur[E_NUM];
  int tid = threadIdx.x;
  if (tid < E_NUM) cur[tid] = bases[blockIdx.x * E_NUM + tid];
  __syncthreads();
  int id = blockIdx.x * 256 + tid;
  int e = top_idx[id];
  int slot = atomicAdd(&cur[e], 1);   // LDS atomic — cheap
  slot_token[slot] = id >> 1;
  slot_w[slot] = top_w[id];
  slot_of[id] = slot;
}

// ================= STAGE 1: dual-gemm-silu (512 blocks) + moe1 (<=320) =================
// m97-style single-buffer K-loop. LDS tiles [128 rows][32 cols] bf16,
// K-contiguous. Frag reads: A row = lane&15, k = (lane>>4)*8+j (ds_read_b128).
// C/D: col = lane&15, row = (lane>>4)*4+rr.
__global__ __launch_bounds__(256) void k_stage1(
    const uint16_t* __restrict__ xb, const uint16_t* __restrict__ b1,
    const uint16_t* __restrict__ b2, uint16_t* __restrict__ hs,
    const uint16_t* __restrict__ w1b, const int* __restrict__ offsets,
    const int* __restrict__ slot_token, const int* __restrict__ tile_e,
    const int* __restrict__ tile_m, const int* __restrict__ tile_cnt,
    uint16_t* __restrict__ hbuf) {
  __shared__ uint16_t smem[3 * 4096];
  const int bid = blockIdx.x;
  const int tid = threadIdx.x, lane = tid & 63, wid = tid >> 6;
  const int wm = wid >> 1, wn = wid & 1;
  const int r = lane & 15, q = lane >> 4;
  const int row0 = tid >> 2, col8 = (tid & 3) * 8;

  if (bid < DUAL_BLOCKS) {
    // ---- dual GEMM: Hs = silu(X sfc1^T) * (X sfc2^T) ----
    const int bm0 = (bid & 31) * 128, bn0 = (bid >> 5) * 128;
    uint16_t* sA = smem; uint16_t* sB1 = smem + 4096; uint16_t* sB2 = smem + 8192;
    f32x4 acc1[4][4], acc2[4][4];
#pragma unroll
    for (int i = 0; i < 4; i++)
#pragma unroll
      for (int j = 0; j < 4; j++) {
        acc1[i][j] = (f32x4){0.f, 0.f, 0.f, 0.f};
        acc2[i][j] = (f32x4){0.f, 0.f, 0.f, 0.f};
      }
    const uint16_t* ga0 = xb + (size_t)(bm0 + row0) * D_DIM + col8;
    const uint16_t* ga1 = ga0 + 64 * D_DIM;
    const uint16_t* gb10 = b1 + (size_t)(bn0 + row0) * D_DIM + col8;
    const uint16_t* gb11 = gb10 + 64 * D_DIM;
    const uint16_t* gb20 = b2 + (size_t)(bn0 + row0) * D_DIM + col8;
    const uint16_t* gb21 = gb20 + 64 * D_DIM;
    for (int kt = 0; kt < D_DIM; kt += 32) {
      gl_lds16(ga0, sA + wid * 512);   gl_lds16(ga1, sA + 2048 + wid * 512);
      gl_lds16(gb10, sB1 + wid * 512); gl_lds16(gb11, sB1 + 2048 + wid * 512);
      gl_lds16(gb20, sB2 + wid * 512); gl_lds16(gb21, sB2 + 2048 + wid * 512);
      ga0 += 32; ga1 += 32; gb10 += 32; gb11 += 32; gb20 += 32; gb21 += 32;
      __syncthreads();
      bf16x8 a[4];
#pragma unroll
      for (int i = 0; i < 4; i++)
        a[i] = *(const bf16x8*)(sA + (wm * 64 + i * 16 + r) * 32 + q * 8);
#pragma unroll
      for (int j = 0; j < 4; j++) {
        bf16x8 b = *(const bf16x8*)(sB1 + (wn * 64 + j * 16 + r) * 32 + q * 8);
#pragma unroll
        for (int i = 0; i < 4; i++)
          acc1[i][j] = __builtin_amdgcn_mfma_f32_16x16x32_bf16(a[i], b, acc1[i][j], 0, 0, 0);
      }
#pragma unroll
      for (int j = 0; j < 4; j++) {
        bf16x8 b = *(const bf16x8*)(sB2 + (wn * 64 + j * 16 + r) * 32 + q * 8);
#pragma unroll
        for (int i = 0; i < 4; i++)
          acc2[i][j] = __builtin_amdgcn_mfma_f32_16x16x32_bf16(a[i], b, acc2[i][j], 0, 0, 0);
      }
      __syncthreads();
    }
#pragma unroll
    for (int i = 0; i < 4; i++)
#pragma unroll
      for (int j = 0; j < 4; j++)
#pragma unroll
        for (int rr = 0; rr < 4; rr++) {
          int row = bm0 + wm * 64 + i * 16 + q * 4 + rr;
          int col = bn0 + wn * 64 + j * 16 + r;
          hs[(size_t)row * S_DIM + col] = f2bf(silu_f(acc1[i][j][rr]) * acc2[i][j][rr]);
        }
  } else {
    // ---- moe1: h = silu(Xg @ w1[e]^T) ----
    int idx = bid - DUAL_BLOCKS;
    int t = idx >> 2;
    if (t >= tile_cnt[0]) return;
    const int n0 = (idx & 3) * 128;
    const int e = tile_e[t], m0 = tile_m[t];
    const int base = offsets[e];
    const int ne = offsets[e + 1] - base;
    uint16_t* sA = smem; uint16_t* sB = smem + 4096;
    f32x4 acc[4][4];
#pragma unroll
    for (int i = 0; i < 4; i++)
#pragma unroll
      for (int j = 0; j < 4; j++) acc[i][j] = (f32x4){0.f, 0.f, 0.f, 0.f};
    const int e0 = min(m0 + row0, ne - 1);
    const int e1 = min(m0 + row0 + 64, ne - 1);
    const uint16_t* ga0 = xb + (size_t)slot_token[base + e0] * D_DIM + col8;
    const uint16_t* ga1 = xb + (size_t)slot_token[base + e1] * D_DIM + col8;
    const uint16_t* wbase = w1b + (size_t)e * H_DIM * D_DIM;
    const uint16_t* gb0 = wbase + (size_t)(n0 + row0) * D_DIM + col8;
    const uint16_t* gb1 = gb0 + 64 * D_DIM;
    for (int kt = 0; kt < D_DIM; kt += 32) {
      gl_lds16(ga0, sA + wid * 512); gl_lds16(ga1, sA + 2048 + wid * 512);
      gl_lds16(gb0, sB + wid * 512); gl_lds16(gb1, sB + 2048 + wid * 512);
      ga0 += 32; ga1 += 32; gb0 += 32; gb1 += 32;
      __syncthreads();
      bf16x8 a[4], bb[4];
#pragma unroll
      for (int i = 0; i < 4; i++)
        a[i] = *(const bf16x8*)(sA + (wm * 64 + i * 16 + r) * 32 + q * 8);
#pragma unroll
      for (int j = 0; j < 4; j++)
        bb[j] = *(const bf16x8*)(sB + (wn * 64 + j * 16 + r) * 32 + q * 8);
#pragma unroll
      for (int i = 0; i < 4; i++)
#pragma unroll
        for (int j = 0; j < 4; j++)
          acc[i][j] = __builtin_amdgcn_mfma_f32_16x16x32_bf16(a[i], bb[j], acc[i][j], 0, 0, 0);
      __syncthreads();
    }
#pragma unroll
    for (int i = 0; i < 4; i++)
#pragma unroll
      for (int j = 0; j < 4; j++)
#pragma unroll
        for (int rr = 0; rr < 4; rr++) {
          int ent = m0 + wm * 64 + i * 16 + q * 4 + rr;
          if (ent < ne) {
            int col = n0 + wn * 64 + j * 16 + r;
            hbuf[(size_t)(base + ent) * H_DIM + col] = f2bf(silu_f(acc[i][j][rr]));
          }
        }
  }
}

// ================= STAGE 2: shared_out (256 blocks) + moe2 (<=640) =================
__global__ __launch_bounds__(256) void k_stage2(
    const uint16_t* __restrict__ hsb, const uint16_t* __restrict__ sfc3b,
    float* __restrict__ out, const uint16_t* __restrict__ hbuf,
    const uint16_t* __restrict__ w2b, const int* __restrict__ offsets,
    const float* __restrict__ slot_w, const int* __restrict__ tile_e,
    const int* __restrict__ tile_m, const int* __restrict__ tile_cnt,
    uint16_t* __restrict__ slot_out) {
  __shared__ uint16_t smem[2 * 4096];
  const int bid = blockIdx.x;
  const int tid = threadIdx.x, lane = tid & 63, wid = tid >> 6;
  const int wm = wid >> 1, wn = wid & 1;
  const int r = lane & 15, q = lane >> 4;
  const int row0 = tid >> 2, col8 = (tid & 3) * 8;
  uint16_t* sA = smem; uint16_t* sB = smem + 4096;

  if (bid < SHOUT_BLOCKS) {
    // ---- shared_out: out = Hs @ sfc3^T (fp32 stores) ----
    const int bm0 = (bid & 31) * 128, bn0 = (bid >> 5) * 128;
    f32x4 acc[4][4];
#pragma unroll
    for (int i = 0; i < 4; i++)
#pragma unroll
      for (int j = 0; j < 4; j++) acc[i][j] = (f32x4){0.f, 0.f, 0.f, 0.f};
    const uint16_t* ga0 = hsb + (size_t)(bm0 + row0) * S_DIM + col8;
    const uint16_t* ga1 = ga0 + (size_t)64 * S_DIM;
    const uint16_t* gb0 = sfc3b + (size_t)(bn0 + row0) * S_DIM + col8;
    const uint16_t* gb1 = gb0 + (size_t)64 * S_DIM;
    for (int kt = 0; kt < S_DIM; kt += 32) {
      gl_lds16(ga0, sA + wid * 512); gl_lds16(ga1, sA + 2048 + wid * 512);
      gl_lds16(gb0, sB + wid * 512); gl_lds16(gb1, sB + 2048 + wid * 512);
      ga0 += 32; ga1 += 32; gb0 += 32; gb1 += 32;
      __syncthreads();
      bf16x8 a[4], bb[4];
#pragma unroll
      for (int i = 0; i < 4; i++)
        a[i] = *(const bf16x8*)(sA + (wm * 64 + i * 16 + r) * 32 + q * 8);
#pragma unroll
      for (int j = 0; j < 4; j++)
        bb[j] = *(const bf16x8*)(sB + (wn * 64 + j * 16 + r) * 32 + q * 8);
#pragma unroll
      for (int i = 0; i < 4; i++)
#pragma unroll
        for (int j = 0; j < 4; j++)
          acc[i][j] = __builtin_amdgcn_mfma_f32_16x16x32_bf16(a[i], bb[j], acc[i][j], 0, 0, 0);
      __syncthreads();
    }
#pragma unroll
    for (int i = 0; i < 4; i++)
#pragma unroll
      for (int j = 0; j < 4; j++)
#pragma unroll
        for (int rr = 0; rr < 4; rr++) {
          int row = bm0 + wm * 64 + i * 16 + q * 4 + rr;
          int col = bn0 + wn * 64 + j * 16 + r;
          out[(size_t)row * D_DIM + col] = acc[i][j][rr];
        }
  } else {
    // ---- moe2: slot_out = w * (h @ w2[e]^T) (bf16 stores) ----
    int idx = bid - SHOUT_BLOCKS;
    int t = idx >> 3;
    if (t >= tile_cnt[0]) return;
    const int n0 = (idx & 7) * 128;
    const int e = tile_e[t], m0 = tile_m[t];
    const int base = offsets[e];
    const int ne = offsets[e + 1] - base;
    f32x4 acc[4][4];
#pragma unroll
    for (int i = 0; i < 4; i++)
#pragma unroll
      for (int j = 0; j < 4; j++) acc[i][j] = (f32x4){0.f, 0.f, 0.f, 0.f};
    const int e0 = min(m0 + row0, ne - 1);
    const int e1 = min(m0 + row0 + 64, ne - 1);
    const uint16_t* ga0 = hbuf + (size_t)(base + e0) * H_DIM + col8;
    const uint16_t* ga1 = hbuf + (size_t)(base + e1) * H_DIM + col8;
    const uint16_t* wbase = w2b + (size_t)e * D_DIM * H_DIM;
    const uint16_t* gb0 = wbase + (size_t)(n0 + row0) * H_DIM + col8;
    const uint16_t* gb1 = gb0 + 64 * H_DIM;
    for (int kt = 0; kt < H_DIM; kt += 32) {
      gl_lds16(ga0, sA + wid * 512); gl_lds16(ga1, sA + 2048 + wid * 512);
      gl_lds16(gb0, sB + wid * 512); gl_lds16(gb1, sB + 2048 + wid * 512);
      ga0 += 32; ga1 += 32; gb0 += 32; gb1 += 32;
      __syncthreads();
      bf16x8 a[4], bb[4];
#pragma unroll
      for (int i = 0; i < 4; i++)
        a[i] = *(const bf16x8*)(sA + (wm * 64 + i * 16 + r) * 32 + q * 8);
#pragma unroll
      for (int j = 0; j < 4; j++)
        bb[j] = *(const bf16x8*)(sB + (wn * 64 + j * 16 + r) * 32 + q * 8);
#pragma unroll
      for (int i = 0; i < 4; i++)
#pragma unroll
        for (int j = 0; j < 4; j++)
          acc[i][j] = __builtin_amdgcn_mfma_f32_16x16x32_bf16(a[i], bb[j], acc[i][j], 0, 0, 0);
      __syncthreads();
    }
#pragma unroll
    for (int i = 0; i < 4; i++) {
      int ent_base = m0 + wm * 64 + i * 16 + q * 4;
#pragma unroll
      for (int rr = 0; rr < 4; rr++) {
        int ent = ent_base + rr;
        if (ent < ne) {
          float w = slot_w[base + ent];
          uint16_t* orow = slot_out + (size_t)(base + ent) * D_DIM;
#pragma unroll
          for (int j = 0; j < 4; j++) {
            int col = n0 + wn * 64 + j * 16 + r;
            orow[col] = f2bf(w * acc[i][j][rr]);
          }
        }
      }
    }
  }
}

// ---------------- combine: out[t] += slot_out[s0] + slot_out[s1] (bf16 in) ----------------
__global__ __launch_bounds__(256) void k_combine(
    const uint16_t* __restrict__ slot_out, const int* __restrict__ slot_of,
    float* __restrict__ out) {
  int t = blockIdx.x;
  int c = threadIdx.x;
  int s0 = slot_of[t * 2], s1 = slot_of[t * 2 + 1];
  ushort4 a = ((const ushort4*)(slot_out + (size_t)s0 * D_DIM))[c];
  ushort4 b = ((const ushort4*)(slot_out + (size_t)s1 * D_DIM))[c];
  float4* po = (float4*)(out + (size_t)t * D_DIM) + c;
  float4 o = *po;
  o.x += bf2f(a.x) + bf2f(b.x);
  o.y += bf2f(a.y) + bf2f(b.y);
  o.z += bf2f(a.z) + bf2f(b.z);
  o.w += bf2f(a.w) + bf2f(b.w);
  *po = o;
}

// ---------------- launch ----------------
extern "C" void kernel_launch(void* const* d_in, const int* in_sizes, int n_in,
                              void* d_out, int out_size, void* d_ws, size_t ws_size,
                              hipStream_t stream) {
  const float* x     = (const float*)d_in[0];
  const float* gatew = (const float*)d_in[1];
  const float* w1    = (const float*)d_in[2];
  const float* w2    = (const float*)d_in[3];
  const float* sfc1  = (const float*)d_in[4];
  const float* sfc2  = (const float*)d_in[5];
  const float* sfc3  = (const float*)d_in[6];
  float* out = (float*)d_out;

  uint8_t* ws = (uint8_t*)d_ws;
  size_t off = 0;
  auto alloc = [&](size_t bytes) {
    void* p = ws + off;
    off = (off + bytes + 255) & ~(size_t)255;
    return p;
  };
  uint16_t* xb    = (uint16_t*)alloc((size_t)T_TOK * D_DIM * 2);
  uint16_t* sfc1b = (uint16_t*)alloc((size_t)S_DIM * D_DIM * 2);
  uint16_t* sfc2b = (uint16_t*)alloc((size_t)S_DIM * D_DIM * 2);
  uint16_t* sfc3b = (uint16_t*)alloc((size_t)D_DIM * S_DIM * 2);
  uint16_t* w1b   = (uint16_t*)alloc((size_t)E_NUM * H_DIM * D_DIM * 2);
  uint16_t* w2b   = (uint16_t*)alloc((size_t)E_NUM * D_DIM * H_DIM * 2);
  uint16_t* hsb   = (uint16_t*)alloc((size_t)T_TOK * S_DIM * 2);
  uint16_t* hbuf  = (uint16_t*)alloc((size_t)2 * T_TOK * H_DIM * 2);
  uint16_t* slot_out = (uint16_t*)alloc((size_t)2 * T_TOK * D_DIM * 2);
  float4* gwT4    = (float4*)alloc((size_t)D_DIM / 4 * E_NUM * 16);
  int*   top_idx  = (int*)alloc((size_t)T_TOK * 2 * 4);
  float* top_w    = (float*)alloc((size_t)T_TOK * 2 * 4);
  int*   partial  = (int*)alloc(32 * E_NUM * 4);
  int*   bases    = (int*)alloc(32 * E_NUM * 4);
  int*   offsets  = (int*)alloc((E_NUM + 1) * 4);
  int*   tile_e   = (int*)alloc(MOE1_TILES_MAX * 4);
  int*   tile_m   = (int*)alloc(MOE1_TILES_MAX * 4);
  int*   tile_cnt = (int*)alloc(4);
  int*   slot_token = (int*)alloc((size_t)2 * T_TOK * 4);
  float* slot_w   = (float*)alloc((size_t)2 * T_TOK * 4);
  int*   slot_of  = (int*)alloc((size_t)2 * T_TOK * 4);

  // 1. fused casts + gw transpose
  k_cast_all<<<(N4_TOT + 255) / 256, 256, 0, stream>>>(
      x, sfc1, sfc2, sfc3, w1, w2, xb, sfc1b, sfc2b, sfc3b, w1b, w2b);
  k_gwT<<<(E_NUM * D_DIM / 4 + 255) / 256, 256, 0, stream>>>(gatew, gwT4);
  // 2. router + counting sort (no contended global atomics)
  k_router<<<T_TOK / 4, 256, 0, stream>>>(x, gwT4, top_idx, top_w);
  k_hist<<<32, 256, 0, stream>>>(top_idx, partial);
  k_scan<<<1, 64, 0, stream>>>(partial, bases, offsets, tile_e, tile_m, tile_cnt);
  k_scatter<<<32, 256, 0, stream>>>(top_idx, top_w, bases, slot_token, slot_w, slot_of);
  // 3. stage1: dual-gemm-silu + moe1 fused (independent GEMMs co-resident)
  k_stage1<<<DUAL_BLOCKS + MOE1_TILES_MAX * 4, 256, 0, stream>>>(
      xb, sfc1b, sfc2b, hsb, w1b, offsets, slot_token, tile_e, tile_m, tile_cnt, hbuf);
  // 4. stage2: shared_out + moe2 fused
  k_stage2<<<SHOUT_BLOCKS + MOE1_TILES_MAX * 8, 256, 0, stream>>>(
      hsb, sfc3b, out, hbuf, w2b, offsets, slot_w, tile_e, tile_m, tile_cnt, slot_out);
  // 5. combine MoE slots into output
  k_combine<<<T_TOK, 256, 0, stream>>>(slot_out, slot_of, out);
}

// Round 7
// 305.995 us; speedup vs baseline: 1.9398x; 1.1421x over previous
//
#include <hip/hip_runtime.h>
#include <stdint.h>

// Problem constants (B=2, L=2048 -> T=4096)
#define T_TOK 4096
#define D_DIM 1024
#define H_DIM 512
#define E_NUM 16
#define S_DIM 2048

#define DUAL_BLOCKS 512   // (T/128) x (S/128) = 32 x 16
#define MOE1_TILES_MAX 80 // sum ceil(ne/128) <= 64 + 16
#define SHOUT_BLOCKS 256  // (T/128) x (D/128) = 32 x 8

typedef __attribute__((ext_vector_type(8))) __bf16 bf16x8;
typedef __attribute__((ext_vector_type(4))) float f32x4;

__device__ __forceinline__ uint16_t f2bf(float f) {
  uint32_t u = __float_as_uint(f);
  u += 0x7fffu + ((u >> 16) & 1u);   // round-to-nearest-even
  return (uint16_t)(u >> 16);
}

__device__ __forceinline__ float bf2f(uint16_t u) {
  return __uint_as_float(((uint32_t)u) << 16);
}

__device__ __forceinline__ float silu_f(float v) {
  return v / (1.f + __expf(-v));
}

// ---------------- fused fp32 -> bf16 cast of all six tensors ----------------
#define N4_X (T_TOK * D_DIM / 4)         // 1048576
#define N4_S (S_DIM * D_DIM / 4)         // 524288
#define N4_W (E_NUM * H_DIM * D_DIM / 4) // 2097152
#define N4_TOT (N4_X + 3 * N4_S + 2 * N4_W)

__global__ __launch_bounds__(256) void k_cast_all(
    const float* __restrict__ x, const float* __restrict__ sfc1,
    const float* __restrict__ sfc2, const float* __restrict__ sfc3,
    const float* __restrict__ w1, const float* __restrict__ w2,
    uint16_t* __restrict__ xb, uint16_t* __restrict__ s1b,
    uint16_t* __restrict__ s2b, uint16_t* __restrict__ s3b,
    uint16_t* __restrict__ w1b, uint16_t* __restrict__ w2b) {
  int i = blockIdx.x * 256 + threadIdx.x;
  if (i >= N4_TOT) return;
  const float* src; uint16_t* dst; int off;
  if (i < N4_X)                    { src = x;    dst = xb;  off = 0; }
  else if (i < N4_X + N4_S)        { src = sfc1; dst = s1b; off = N4_X; }
  else if (i < N4_X + 2 * N4_S)    { src = sfc2; dst = s2b; off = N4_X + N4_S; }
  else if (i < N4_X + 3 * N4_S)    { src = sfc3; dst = s3b; off = N4_X + 2 * N4_S; }
  else if (i < N4_X + 3 * N4_S + N4_W) { src = w1; dst = w1b; off = N4_X + 3 * N4_S; }
  else                             { src = w2;  dst = w2b; off = N4_X + 3 * N4_S + N4_W; }
  int j = i - off;
  float4 v = ((const float4*)src)[j];
  ushort4 o;
  o.x = f2bf(v.x); o.y = f2bf(v.y); o.z = f2bf(v.z); o.w = f2bf(v.w);
  ((ushort4*)dst)[j] = o;
}

// ---------------- gw transpose: [E][D] -> [D/4][E] of float4 ----------------
__global__ void k_gwT(const float* __restrict__ gw, float4* __restrict__ gwT4) {
  int tid = blockIdx.x * 256 + threadIdx.x;  // 4096 threads
  if (tid >= E_NUM * (D_DIM / 4)) return;
  int k4 = tid & (D_DIM / 4 - 1);
  int e = tid >> 8;
  float4 v = ((const float4*)(gw + (size_t)e * D_DIM))[k4];
  gwT4[(size_t)k4 * E_NUM + e] = v;
}

// ---------------- router: fp32 logits, in-register top-2, NO atomics ----------------
__global__ __launch_bounds__(256) void k_router(
    const float* __restrict__ x, const float4* __restrict__ gwT4,
    int* __restrict__ top_idx, float* __restrict__ top_w) {
  const int wid = threadIdx.x >> 6, lane = threadIdx.x & 63;
  const int t = blockIdx.x * 4 + wid;
  const int e = lane & 15, q = lane >> 4;
  const float4* xr4 = (const float4*)(x + (size_t)t * D_DIM) + q * 64;
  const float4* g4 = gwT4 + (size_t)q * 64 * E_NUM + e;
  float acc = 0.f;
#pragma unroll 8
  for (int i = 0; i < 64; i++) {
    float4 xv = xr4[i];
    float4 gv = g4[(size_t)i * E_NUM];
    acc += xv.x * gv.x + xv.y * gv.y + xv.z * gv.z + xv.w * gv.w;
  }
  acc += __shfl_xor(acc, 16, 64);
  acc += __shfl_xor(acc, 32, 64);
  float v1 = acc; int i1 = e;
#pragma unroll
  for (int off = 1; off < 16; off <<= 1) {
    float ov = __shfl_xor(v1, off, 64);
    int oi = __shfl_xor(i1, off, 64);
    if (ov > v1 || (ov == v1 && oi < i1)) { v1 = ov; i1 = oi; }
  }
  float v2 = (e == i1) ? -1e30f : acc; int i2 = e;
#pragma unroll
  for (int off = 1; off < 16; off <<= 1) {
    float ov = __shfl_xor(v2, off, 64);
    int oi = __shfl_xor(i2, off, 64);
    if (ov > v2 || (ov == v2 && oi < i2)) { v2 = ov; i2 = oi; }
  }
  if (lane == 0) {
    float w0 = 1.f / (1.f + __expf(v2 - v1));
    top_idx[t * 2] = i1; top_idx[t * 2 + 1] = i2;
    top_w[t * 2] = w0;  top_w[t * 2 + 1] = 1.f - w0;
  }
}

// ---------------- counting sort (no global atomics) ----------------
__global__ __launch_bounds__(256) void k_hist(const int* __restrict__ top_idx,
                                              int* __restrict__ partial) {
  __shared__ int h[E_NUM];
  int tid = threadIdx.x;
  if (tid < E_NUM) h[tid] = 0;
  __syncthreads();
  int id = blockIdx.x * 256 + tid;
  atomicAdd(&h[top_idx[id]], 1);
  __syncthreads();
  if (tid < E_NUM) partial[blockIdx.x * E_NUM + tid] = h[tid];
}

__global__ void k_scan(const int* __restrict__ partial, int* __restrict__ bases,
                       int* __restrict__ offsets, int* __restrict__ tile_e,
                       int* __restrict__ tile_m, int* __restrict__ tile_cnt) {
  __shared__ int tot[E_NUM];
  int e = threadIdx.x;
  if (e < E_NUM) {
    int run = 0;
    for (int b = 0; b < 32; b++) { bases[b * E_NUM + e] = run; run += partial[b * E_NUM + e]; }
    tot[e] = run;
  }
  __syncthreads();
  if (e == 0) {
    int s = 0;
    for (int i = 0; i < E_NUM; i++) { offsets[i] = s; s += tot[i]; }
    offsets[E_NUM] = s;
    int cnt = 0;
    for (int i = 0; i < E_NUM; i++) {
      for (int m0 = 0; m0 < tot[i]; m0 += 128) {
        tile_e[cnt] = i; tile_m[cnt] = m0; cnt++;
      }
    }
    tile_cnt[0] = cnt;
  }
  __syncthreads();
  if (e < E_NUM) {
    int off = offsets[e];
    for (int b = 0; b < 32; b++) bases[b * E_NUM + e] += off;
  }
}

__global__ __launch_bounds__(256) void k_scatter(
    const int* __restrict__ top_idx, const float* __restrict__ top_w,
    const int* __restrict__ bases, int* __restrict__ slot_token,
    float* __restrict__ slot_w, int* __restrict__ slot_of) {
  __shared__ int cur[E_NUM];
  int tid = threadIdx.x;
  if (tid < E_NUM) cur[tid] = bases[blockIdx.x * E_NUM + tid];
  __syncthreads();
  int id = blockIdx.x * 256 + tid;
  int e = top_idx[id];
  int slot = atomicAdd(&cur[e], 1);   // LDS atomic — cheap
  slot_token[slot] = id >> 1;
  slot_w[slot] = top_w[id];
  slot_of[id] = slot;
}

// ================= GEMM K-loop: register-prefetch pipeline =================
// Tile layout in LDS: [128 rows][32 cols] bf16, K-contiguous, element offset
// of thread tid's 16B chunk = tid*8 (first 64 rows) / 2048 + tid*8 (rows
// 64-127). Globals are prefetched into VGPRs one iteration ahead; the barrier
// drains only the ds_write (lgkmcnt) — global latency hides behind MFMA.
// Frag reads: A row = lane&15, k = (lane>>4)*8+j (ds_read_b128).
// C/D: col = lane&15, row = (lane>>4)*4+rr.

// ================= STAGE 1: dual-gemm-silu (512 blocks) + moe1 =================
__global__ __launch_bounds__(256) void k_stage1(
    const uint16_t* __restrict__ xb, const uint16_t* __restrict__ b1,
    const uint16_t* __restrict__ b2, uint16_t* __restrict__ hs,
    const uint16_t* __restrict__ w1b, const int* __restrict__ offsets,
    const int* __restrict__ slot_token, const int* __restrict__ tile_e,
    const int* __restrict__ tile_m, const int* __restrict__ tile_cnt,
    uint16_t* __restrict__ hbuf) {
  __shared__ uint16_t smem[6 * 4096];   // dual: 3 tiles x 2 bufs (48 KB)
  const int bid = blockIdx.x;
  const int tid = threadIdx.x, lane = tid & 63, wid = tid >> 6;
  const int wm = wid >> 1, wn = wid & 1;
  const int r = lane & 15, q = lane >> 4;
  const int row0 = tid >> 2, col8 = (tid & 3) * 8;
  const int st0 = tid * 8, st1 = 2048 + tid * 8;

  if (bid < DUAL_BLOCKS) {
    const int bm0 = (bid & 31) * 128, bn0 = (bid >> 5) * 128;
    uint16_t* sA = smem;            // 2 bufs of 4096
    uint16_t* sB1 = smem + 8192;
    uint16_t* sB2 = smem + 16384;
    f32x4 acc1[4][4], acc2[4][4];
#pragma unroll
    for (int i = 0; i < 4; i++)
#pragma unroll
      for (int j = 0; j < 4; j++) {
        acc1[i][j] = (f32x4){0.f, 0.f, 0.f, 0.f};
        acc2[i][j] = (f32x4){0.f, 0.f, 0.f, 0.f};
      }
    const uint16_t* ga0 = xb + (size_t)(bm0 + row0) * D_DIM + col8;
    const uint16_t* ga1 = ga0 + 64 * D_DIM;
    const uint16_t* gb10 = b1 + (size_t)(bn0 + row0) * D_DIM + col8;
    const uint16_t* gb11 = gb10 + 64 * D_DIM;
    const uint16_t* gb20 = b2 + (size_t)(bn0 + row0) * D_DIM + col8;
    const uint16_t* gb21 = gb20 + 64 * D_DIM;

    uint4 pA0, pA1, pB10, pB11, pB20, pB21;
    pA0 = *(const uint4*)ga0;   pA1 = *(const uint4*)ga1;
    pB10 = *(const uint4*)gb10; pB11 = *(const uint4*)gb11;
    pB20 = *(const uint4*)gb20; pB21 = *(const uint4*)gb21;
    ga0 += 32; ga1 += 32; gb10 += 32; gb11 += 32; gb20 += 32; gb21 += 32;
    *(uint4*)(sA + st0) = pA0;   *(uint4*)(sA + st1) = pA1;
    *(uint4*)(sB1 + st0) = pB10; *(uint4*)(sB1 + st1) = pB11;
    *(uint4*)(sB2 + st0) = pB20; *(uint4*)(sB2 + st1) = pB21;
    __syncthreads();

    int cur = 0;
    for (int kt = 32; kt < D_DIM; kt += 32) {
      // prefetch next tile into registers (latency hidden by MFMA below)
      pA0 = *(const uint4*)ga0;   pA1 = *(const uint4*)ga1;
      pB10 = *(const uint4*)gb10; pB11 = *(const uint4*)gb11;
      pB20 = *(const uint4*)gb20; pB21 = *(const uint4*)gb21;
      ga0 += 32; ga1 += 32; gb10 += 32; gb11 += 32; gb20 += 32; gb21 += 32;
      {
        const uint16_t* A = sA + cur * 4096;
        const uint16_t* B1 = sB1 + cur * 4096;
        const uint16_t* B2 = sB2 + cur * 4096;
        bf16x8 a[4];
#pragma unroll
        for (int i = 0; i < 4; i++)
          a[i] = *(const bf16x8*)(A + (wm * 64 + i * 16 + r) * 32 + q * 8);
#pragma unroll
        for (int j = 0; j < 4; j++) {
          bf16x8 b = *(const bf16x8*)(B1 + (wn * 64 + j * 16 + r) * 32 + q * 8);
#pragma unroll
          for (int i = 0; i < 4; i++)
            acc1[i][j] = __builtin_amdgcn_mfma_f32_16x16x32_bf16(a[i], b, acc1[i][j], 0, 0, 0);
        }
#pragma unroll
        for (int j = 0; j < 4; j++) {
          bf16x8 b = *(const bf16x8*)(B2 + (wn * 64 + j * 16 + r) * 32 + q * 8);
#pragma unroll
          for (int i = 0; i < 4; i++)
            acc2[i][j] = __builtin_amdgcn_mfma_f32_16x16x32_bf16(a[i], b, acc2[i][j], 0, 0, 0);
        }
      }
      int nxt = cur ^ 1;
      *(uint4*)(sA + nxt * 4096 + st0) = pA0;   *(uint4*)(sA + nxt * 4096 + st1) = pA1;
      *(uint4*)(sB1 + nxt * 4096 + st0) = pB10; *(uint4*)(sB1 + nxt * 4096 + st1) = pB11;
      *(uint4*)(sB2 + nxt * 4096 + st0) = pB20; *(uint4*)(sB2 + nxt * 4096 + st1) = pB21;
      __syncthreads();
      cur = nxt;
    }
    {
      const uint16_t* A = sA + cur * 4096;
      const uint16_t* B1 = sB1 + cur * 4096;
      const uint16_t* B2 = sB2 + cur * 4096;
      bf16x8 a[4];
#pragma unroll
      for (int i = 0; i < 4; i++)
        a[i] = *(const bf16x8*)(A + (wm * 64 + i * 16 + r) * 32 + q * 8);
#pragma unroll
      for (int j = 0; j < 4; j++) {
        bf16x8 b = *(const bf16x8*)(B1 + (wn * 64 + j * 16 + r) * 32 + q * 8);
#pragma unroll
        for (int i = 0; i < 4; i++)
          acc1[i][j] = __builtin_amdgcn_mfma_f32_16x16x32_bf16(a[i], b, acc1[i][j], 0, 0, 0);
      }
#pragma unroll
      for (int j = 0; j < 4; j++) {
        bf16x8 b = *(const bf16x8*)(B2 + (wn * 64 + j * 16 + r) * 32 + q * 8);
#pragma unroll
        for (int i = 0; i < 4; i++)
          acc2[i][j] = __builtin_amdgcn_mfma_f32_16x16x32_bf16(a[i], b, acc2[i][j], 0, 0, 0);
      }
    }
#pragma unroll
    for (int i = 0; i < 4; i++)
#pragma unroll
      for (int j = 0; j < 4; j++)
#pragma unroll
        for (int rr = 0; rr < 4; rr++) {
          int row = bm0 + wm * 64 + i * 16 + q * 4 + rr;
          int col = bn0 + wn * 64 + j * 16 + r;
          hs[(size_t)row * S_DIM + col] = f2bf(silu_f(acc1[i][j][rr]) * acc2[i][j][rr]);
        }
  } else {
    // ---- moe1: h = silu(Xg @ w1[e]^T) ----
    int idx = bid - DUAL_BLOCKS;
    int t = idx >> 2;
    if (t >= tile_cnt[0]) return;
    const int n0 = (idx & 3) * 128;
    const int e = tile_e[t], m0 = tile_m[t];
    const int base = offsets[e];
    const int ne = offsets[e + 1] - base;
    uint16_t* sA = smem;
    uint16_t* sB = smem + 8192;
    f32x4 acc[4][4];
#pragma unroll
    for (int i = 0; i < 4; i++)
#pragma unroll
      for (int j = 0; j < 4; j++) acc[i][j] = (f32x4){0.f, 0.f, 0.f, 0.f};
    const int e0 = min(m0 + row0, ne - 1);
    const int e1 = min(m0 + row0 + 64, ne - 1);
    const uint16_t* ga0 = xb + (size_t)slot_token[base + e0] * D_DIM + col8;
    const uint16_t* ga1 = xb + (size_t)slot_token[base + e1] * D_DIM + col8;
    const uint16_t* wbase = w1b + (size_t)e * H_DIM * D_DIM;
    const uint16_t* gb0 = wbase + (size_t)(n0 + row0) * D_DIM + col8;
    const uint16_t* gb1 = gb0 + 64 * D_DIM;

    uint4 pA0, pA1, pB0, pB1;
    pA0 = *(const uint4*)ga0; pA1 = *(const uint4*)ga1;
    pB0 = *(const uint4*)gb0; pB1 = *(const uint4*)gb1;
    ga0 += 32; ga1 += 32; gb0 += 32; gb1 += 32;
    *(uint4*)(sA + st0) = pA0; *(uint4*)(sA + st1) = pA1;
    *(uint4*)(sB + st0) = pB0; *(uint4*)(sB + st1) = pB1;
    __syncthreads();

    int cur = 0;
    for (int kt = 32; kt < D_DIM; kt += 32) {
      pA0 = *(const uint4*)ga0; pA1 = *(const uint4*)ga1;
      pB0 = *(const uint4*)gb0; pB1 = *(const uint4*)gb1;
      ga0 += 32; ga1 += 32; gb0 += 32; gb1 += 32;
      {
        const uint16_t* A = sA + cur * 4096;
        const uint16_t* B = sB + cur * 4096;
        bf16x8 a[4], bb[4];
#pragma unroll
        for (int i = 0; i < 4; i++)
          a[i] = *(const bf16x8*)(A + (wm * 64 + i * 16 + r) * 32 + q * 8);
#pragma unroll
        for (int j = 0; j < 4; j++)
          bb[j] = *(const bf16x8*)(B + (wn * 64 + j * 16 + r) * 32 + q * 8);
#pragma unroll
        for (int i = 0; i < 4; i++)
#pragma unroll
          for (int j = 0; j < 4; j++)
            acc[i][j] = __builtin_amdgcn_mfma_f32_16x16x32_bf16(a[i], bb[j], acc[i][j], 0, 0, 0);
      }
      int nxt = cur ^ 1;
      *(uint4*)(sA + nxt * 4096 + st0) = pA0; *(uint4*)(sA + nxt * 4096 + st1) = pA1;
      *(uint4*)(sB + nxt * 4096 + st0) = pB0; *(uint4*)(sB + nxt * 4096 + st1) = pB1;
      __syncthreads();
      cur = nxt;
    }
    {
      const uint16_t* A = sA + cur * 4096;
      const uint16_t* B = sB + cur * 4096;
      bf16x8 a[4], bb[4];
#pragma unroll
      for (int i = 0; i < 4; i++)
        a[i] = *(const bf16x8*)(A + (wm * 64 + i * 16 + r) * 32 + q * 8);
#pragma unroll
      for (int j = 0; j < 4; j++)
        bb[j] = *(const bf16x8*)(B + (wn * 64 + j * 16 + r) * 32 + q * 8);
#pragma unroll
      for (int i = 0; i < 4; i++)
#pragma unroll
        for (int j = 0; j < 4; j++)
          acc[i][j] = __builtin_amdgcn_mfma_f32_16x16x32_bf16(a[i], bb[j], acc[i][j], 0, 0, 0);
    }
#pragma unroll
    for (int i = 0; i < 4; i++)
#pragma unroll
      for (int j = 0; j < 4; j++)
#pragma unroll
        for (int rr = 0; rr < 4; rr++) {
          int ent = m0 + wm * 64 + i * 16 + q * 4 + rr;
          if (ent < ne) {
            int col = n0 + wn * 64 + j * 16 + r;
            hbuf[(size_t)(base + ent) * H_DIM + col] = f2bf(silu_f(acc[i][j][rr]));
          }
        }
  }
}

// ================= STAGE 2: shared_out (256 blocks) + moe2 =================
__global__ __launch_bounds__(256) void k_stage2(
    const uint16_t* __restrict__ hsb, const uint16_t* __restrict__ sfc3b,
    float* __restrict__ out, const uint16_t* __restrict__ hbuf,
    const uint16_t* __restrict__ w2b, const int* __restrict__ offsets,
    const float* __restrict__ slot_w, const int* __restrict__ tile_e,
    const int* __restrict__ tile_m, const int* __restrict__ tile_cnt,
    uint16_t* __restrict__ slot_out) {
  __shared__ uint16_t smem[4 * 4096];   // 2 tiles x 2 bufs (32 KB)
  const int bid = blockIdx.x;
  const int tid = threadIdx.x, lane = tid & 63, wid = tid >> 6;
  const int wm = wid >> 1, wn = wid & 1;
  const int r = lane & 15, q = lane >> 4;
  const int row0 = tid >> 2, col8 = (tid & 3) * 8;
  const int st0 = tid * 8, st1 = 2048 + tid * 8;
  uint16_t* sA = smem;
  uint16_t* sB = smem + 8192;

  if (bid < SHOUT_BLOCKS) {
    // ---- shared_out: out = Hs @ sfc3^T (fp32 stores), K = S_DIM ----
    const int bm0 = (bid & 31) * 128, bn0 = (bid >> 5) * 128;
    f32x4 acc[4][4];
#pragma unroll
    for (int i = 0; i < 4; i++)
#pragma unroll
      for (int j = 0; j < 4; j++) acc[i][j] = (f32x4){0.f, 0.f, 0.f, 0.f};
    const uint16_t* ga0 = hsb + (size_t)(bm0 + row0) * S_DIM + col8;
    const uint16_t* ga1 = ga0 + (size_t)64 * S_DIM;
    const uint16_t* gb0 = sfc3b + (size_t)(bn0 + row0) * S_DIM + col8;
    const uint16_t* gb1 = gb0 + (size_t)64 * S_DIM;

    uint4 pA0, pA1, pB0, pB1;
    pA0 = *(const uint4*)ga0; pA1 = *(const uint4*)ga1;
    pB0 = *(const uint4*)gb0; pB1 = *(const uint4*)gb1;
    ga0 += 32; ga1 += 32; gb0 += 32; gb1 += 32;
    *(uint4*)(sA + st0) = pA0; *(uint4*)(sA + st1) = pA1;
    *(uint4*)(sB + st0) = pB0; *(uint4*)(sB + st1) = pB1;
    __syncthreads();

    int cur = 0;
    for (int kt = 32; kt < S_DIM; kt += 32) {
      pA0 = *(const uint4*)ga0; pA1 = *(const uint4*)ga1;
      pB0 = *(const uint4*)gb0; pB1 = *(const uint4*)gb1;
      ga0 += 32; ga1 += 32; gb0 += 32; gb1 += 32;
      {
        const uint16_t* A = sA + cur * 4096;
        const uint16_t* B = sB + cur * 4096;
        bf16x8 a[4], bb[4];
#pragma unroll
        for (int i = 0; i < 4; i++)
          a[i] = *(const bf16x8*)(A + (wm * 64 + i * 16 + r) * 32 + q * 8);
#pragma unroll
        for (int j = 0; j < 4; j++)
          bb[j] = *(const bf16x8*)(B + (wn * 64 + j * 16 + r) * 32 + q * 8);
#pragma unroll
        for (int i = 0; i < 4; i++)
#pragma unroll
          for (int j = 0; j < 4; j++)
            acc[i][j] = __builtin_amdgcn_mfma_f32_16x16x32_bf16(a[i], bb[j], acc[i][j], 0, 0, 0);
      }
      int nxt = cur ^ 1;
      *(uint4*)(sA + nxt * 4096 + st0) = pA0; *(uint4*)(sA + nxt * 4096 + st1) = pA1;
      *(uint4*)(sB + nxt * 4096 + st0) = pB0; *(uint4*)(sB + nxt * 4096 + st1) = pB1;
      __syncthreads();
      cur = nxt;
    }
    {
      const uint16_t* A = sA + cur * 4096;
      const uint16_t* B = sB + cur * 4096;
      bf16x8 a[4], bb[4];
#pragma unroll
      for (int i = 0; i < 4; i++)
        a[i] = *(const bf16x8*)(A + (wm * 64 + i * 16 + r) * 32 + q * 8);
#pragma unroll
      for (int j = 0; j < 4; j++)
        bb[j] = *(const bf16x8*)(B + (wn * 64 + j * 16 + r) * 32 + q * 8);
#pragma unroll
      for (int i = 0; i < 4; i++)
#pragma unroll
        for (int j = 0; j < 4; j++)
          acc[i][j] = __builtin_amdgcn_mfma_f32_16x16x32_bf16(a[i], bb[j], acc[i][j], 0, 0, 0);
    }
#pragma unroll
    for (int i = 0; i < 4; i++)
#pragma unroll
      for (int j = 0; j < 4; j++)
#pragma unroll
        for (int rr = 0; rr < 4; rr++) {
          int row = bm0 + wm * 64 + i * 16 + q * 4 + rr;
          int col = bn0 + wn * 64 + j * 16 + r;
          out[(size_t)row * D_DIM + col] = acc[i][j][rr];
        }
  } else {
    // ---- moe2: slot_out = w * (h @ w2[e]^T) (bf16 stores), K = H_DIM ----
    int idx = bid - SHOUT_BLOCKS;
    int t = idx >> 3;
    if (t >= tile_cnt[0]) return;
    const int n0 = (idx & 7) * 128;
    const int e = tile_e[t], m0 = tile_m[t];
    const int base = offsets[e];
    const int ne = offsets[e + 1] - base;
    f32x4 acc[4][4];
#pragma unroll
    for (int i = 0; i < 4; i++)
#pragma unroll
      for (int j = 0; j < 4; j++) acc[i][j] = (f32x4){0.f, 0.f, 0.f, 0.f};
    const int e0 = min(m0 + row0, ne - 1);
    const int e1 = min(m0 + row0 + 64, ne - 1);
    const uint16_t* ga0 = hbuf + (size_t)(base + e0) * H_DIM + col8;
    const uint16_t* ga1 = hbuf + (size_t)(base + e1) * H_DIM + col8;
    const uint16_t* wbase = w2b + (size_t)e * D_DIM * H_DIM;
    const uint16_t* gb0 = wbase + (size_t)(n0 + row0) * H_DIM + col8;
    const uint16_t* gb1 = gb0 + 64 * H_DIM;

    uint4 pA0, pA1, pB0, pB1;
    pA0 = *(const uint4*)ga0; pA1 = *(const uint4*)ga1;
    pB0 = *(const uint4*)gb0; pB1 = *(const uint4*)gb1;
    ga0 += 32; ga1 += 32; gb0 += 32; gb1 += 32;
    *(uint4*)(sA + st0) = pA0; *(uint4*)(sA + st1) = pA1;
    *(uint4*)(sB + st0) = pB0; *(uint4*)(sB + st1) = pB1;
    __syncthreads();

    int cur = 0;
    for (int kt = 32; kt < H_DIM; kt += 32) {
      pA0 = *(const uint4*)ga0; pA1 = *(const uint4*)ga1;
      pB0 = *(const uint4*)gb0; pB1 = *(const uint4*)gb1;
      ga0 += 32; ga1 += 32; gb0 += 32; gb1 += 32;
      {
        const uint16_t* A = sA + cur * 4096;
        const uint16_t* B = sB + cur * 4096;
        bf16x8 a[4], bb[4];
#pragma unroll
        for (int i = 0; i < 4; i++)
          a[i] = *(const bf16x8*)(A + (wm * 64 + i * 16 + r) * 32 + q * 8);
#pragma unroll
        for (int j = 0; j < 4; j++)
          bb[j] = *(const bf16x8*)(B + (wn * 64 + j * 16 + r) * 32 + q * 8);
#pragma unroll
        for (int i = 0; i < 4; i++)
#pragma unroll
          for (int j = 0; j < 4; j++)
            acc[i][j] = __builtin_amdgcn_mfma_f32_16x16x32_bf16(a[i], bb[j], acc[i][j], 0, 0, 0);
      }
      int nxt = cur ^ 1;
      *(uint4*)(sA + nxt * 4096 + st0) = pA0; *(uint4*)(sA + nxt * 4096 + st1) = pA1;
      *(uint4*)(sB + nxt * 4096 + st0) = pB0; *(uint4*)(sB + nxt * 4096 + st1) = pB1;
      __syncthreads();
      cur = nxt;
    }
    {
      const uint16_t* A = sA + cur * 4096;
      const uint16_t* B = sB + cur * 4096;
      bf16x8 a[4], bb[4];
#pragma unroll
      for (int i = 0; i < 4; i++)
        a[i] = *(const bf16x8*)(A + (wm * 64 + i * 16 + r) * 32 + q * 8);
#pragma unroll
      for (int j = 0; j < 4; j++)
        bb[j] = *(const bf16x8*)(B + (wn * 64 + j * 16 + r) * 32 + q * 8);
#pragma unroll
      for (int i = 0; i < 4; i++)
#pragma unroll
        for (int j = 0; j < 4; j++)
          acc[i][j] = __builtin_amdgcn_mfma_f32_16x16x32_bf16(a[i], bb[j], acc[i][j], 0, 0, 0);
    }
#pragma unroll
    for (int i = 0; i < 4; i++) {
      int ent_base = m0 + wm * 64 + i * 16 + q * 4;
#pragma unroll
      for (int rr = 0; rr < 4; rr++) {
        int ent = ent_base + rr;
        if (ent < ne) {
          float w = slot_w[base + ent];
          uint16_t* orow = slot_out + (size_t)(base + ent) * D_DIM;
#pragma unroll
          for (int j = 0; j < 4; j++) {
            int col = n0 + wn * 64 + j * 16 + r;
            orow[col] = f2bf(w * acc[i][j][rr]);
          }
        }
      }
    }
  }
}

// ---------------- combine: out[t] += slot_out[s0] + slot_out[s1] (bf16 in) ----------------
__global__ __launch_bounds__(256) void k_combine(
    const uint16_t* __restrict__ slot_out, const int* __restrict__ slot_of,
    float* __restrict__ out) {
  int t = blockIdx.x;
  int c = threadIdx.x;
  int s0 = slot_of[t * 2], s1 = slot_of[t * 2 + 1];
  ushort4 a = ((const ushort4*)(slot_out + (size_t)s0 * D_DIM))[c];
  ushort4 b = ((const ushort4*)(slot_out + (size_t)s1 * D_DIM))[c];
  float4* po = (float4*)(out + (size_t)t * D_DIM) + c;
  float4 o = *po;
  o.x += bf2f(a.x) + bf2f(b.x);
  o.y += bf2f(a.y) + bf2f(b.y);
  o.z += bf2f(a.z) + bf2f(b.z);
  o.w += bf2f(a.w) + bf2f(b.w);
  *po = o;
}

// ---------------- launch ----------------
extern "C" void kernel_launch(void* const* d_in, const int* in_sizes, int n_in,
                              void* d_out, int out_size, void* d_ws, size_t ws_size,
                              hipStream_t stream) {
  const float* x     = (const float*)d_in[0];
  const float* gatew = (const float*)d_in[1];
  const float* w1    = (const float*)d_in[2];
  const float* w2    = (const float*)d_in[3];
  const float* sfc1  = (const float*)d_in[4];
  const float* sfc2  = (const float*)d_in[5];
  const float* sfc3  = (const float*)d_in[6];
  float* out = (float*)d_out;

  uint8_t* ws = (uint8_t*)d_ws;
  size_t off = 0;
  auto alloc = [&](size_t bytes) {
    void* p = ws + off;
    off = (off + bytes + 255) & ~(size_t)255;
    return p;
  };
  uint16_t* xb    = (uint16_t*)alloc((size_t)T_TOK * D_DIM * 2);
  uint16_t* sfc1b = (uint16_t*)alloc((size_t)S_DIM * D_DIM * 2);
  uint16_t* sfc2b = (uint16_t*)alloc((size_t)S_DIM * D_DIM * 2);
  uint16_t* sfc3b = (uint16_t*)alloc((size_t)D_DIM * S_DIM * 2);
  uint16_t* w1b   = (uint16_t*)alloc((size_t)E_NUM * H_DIM * D_DIM * 2);
  uint16_t* w2b   = (uint16_t*)alloc((size_t)E_NUM * D_DIM * H_DIM * 2);
  uint16_t* hsb   = (uint16_t*)alloc((size_t)T_TOK * S_DIM * 2);
  uint16_t* hbuf  = (uint16_t*)alloc((size_t)2 * T_TOK * H_DIM * 2);
  uint16_t* slot_out = (uint16_t*)alloc((size_t)2 * T_TOK * D_DIM * 2);
  float4* gwT4    = (float4*)alloc((size_t)D_DIM / 4 * E_NUM * 16);
  int*   top_idx  = (int*)alloc((size_t)T_TOK * 2 * 4);
  float* top_w    = (float*)alloc((size_t)T_TOK * 2 * 4);
  int*   partial  = (int*)alloc(32 * E_NUM * 4);
  int*   bases    = (int*)alloc(32 * E_NUM * 4);
  int*   offsets  = (int*)alloc((E_NUM + 1) * 4);
  int*   tile_e   = (int*)alloc(MOE1_TILES_MAX * 4);
  int*   tile_m   = (int*)alloc(MOE1_TILES_MAX * 4);
  int*   tile_cnt = (int*)alloc(4);
  int*   slot_token = (int*)alloc((size_t)2 * T_TOK * 4);
  float* slot_w   = (float*)alloc((size_t)2 * T_TOK * 4);
  int*   slot_of  = (int*)alloc((size_t)2 * T_TOK * 4);

  // 1. fused casts + gw transpose
  k_cast_all<<<(N4_TOT + 255) / 256, 256, 0, stream>>>(
      x, sfc1, sfc2, sfc3, w1, w2, xb, sfc1b, sfc2b, sfc3b, w1b, w2b);
  k_gwT<<<(E_NUM * D_DIM / 4 + 255) / 256, 256, 0, stream>>>(gatew, gwT4);
  // 2. router + counting sort (no contended global atomics)
  k_router<<<T_TOK / 4, 256, 0, stream>>>(x, gwT4, top_idx, top_w);
  k_hist<<<32, 256, 0, stream>>>(top_idx, partial);
  k_scan<<<1, 64, 0, stream>>>(partial, bases, offsets, tile_e, tile_m, tile_cnt);
  k_scatter<<<32, 256, 0, stream>>>(top_idx, top_w, bases, slot_token, slot_w, slot_of);
  // 3. stage1: dual-gemm-silu + moe1 (register-prefetch pipelined K-loops)
  k_stage1<<<DUAL_BLOCKS + MOE1_TILES_MAX * 4, 256, 0, stream>>>(
      xb, sfc1b, sfc2b, hsb, w1b, offsets, slot_token, tile_e, tile_m, tile_cnt, hbuf);
  // 4. stage2: shared_out + moe2
  k_stage2<<<SHOUT_BLOCKS + MOE1_TILES_MAX * 8, 256, 0, stream>>>(
      hsb, sfc3b, out, hbuf, w2b, offsets, slot_w, tile_e, tile_m, tile_cnt, slot_out);
  // 5. combine MoE slots into output
  k_combine<<<T_TOK, 256, 0, stream>>>(slot_out, slot_of, out);
}